// Round 1
// baseline (1887.671 us; speedup 1.0000x reference)
//
#include <hip/hip_runtime.h>

#define HH 128          // hidden dim (must equal b1 size)
#define BN_EPS 1e-5f

__device__ inline void atomAddF(float* p, float v) {
    // HW global_atomic_add_f32 (plain atomicAdd may lower to a CAS loop
    // without -munsafe-fp-atomics)
    unsafeAtomicAdd(p, v);
}

__global__ void k_fill1(float* p, int n) {
    int i = blockIdx.x * blockDim.x + threadIdx.x;
    if (i < n) p[i] = 1.0f;
}

__global__ void k_deg(const int* dst, float* deg, int E) {
    int i = blockIdx.x * blockDim.x + threadIdx.x;
    if (i < E) atomAddF(&deg[dst[i]], 1.0f);
}

__global__ void k_rsqrt(float* p, int n) {
    int i = blockIdx.x * blockDim.x + threadIdx.x;
    if (i < n) p[i] = rsqrtf(p[i]);
}

// A [N,K] @ W [K,HH] -> out [N,HH].  K <= 256. 128 threads = 1 col each,
// R=8 rows per block, A-tile staged in LDS (broadcast reads, conflict-free).
__global__ __launch_bounds__(128) void k_gemm(const float* __restrict__ A,
                                              const float* __restrict__ W,
                                              float* __restrict__ out,
                                              int N, int K) {
    const int R = 8;
    __shared__ float As[R * 256];
    int row0 = blockIdx.x * R;
    int tid = threadIdx.x;
    for (int idx = tid; idx < R * K; idx += 128) {
        int r = idx / K;
        int k = idx - r * K;
        int row = row0 + r;
        As[idx] = (row < N) ? A[(size_t)row * K + k] : 0.0f;
    }
    __syncthreads();
    float acc[R];
#pragma unroll
    for (int r = 0; r < R; r++) acc[r] = 0.0f;
#pragma unroll 4
    for (int k = 0; k < K; k++) {
        float wv = W[k * HH + tid];
#pragma unroll
        for (int r = 0; r < R; r++) acc[r] += As[r * K + k] * wv;
    }
#pragma unroll
    for (int r = 0; r < R; r++) {
        int row = row0 + r;
        if (row < N) out[(size_t)row * HH + tid] = acc[r];
    }
}

// agg[dst] += dinv[src]*dinv[dst] * xw[src]   (one thread per (edge, col))
__global__ __launch_bounds__(256) void k_scatter(const float* __restrict__ xw,
                                                 const float* __restrict__ dinv,
                                                 const int* __restrict__ src,
                                                 const int* __restrict__ dst,
                                                 float* __restrict__ agg, int E) {
    int idx = blockIdx.x * 256 + threadIdx.x;           // E*128 < 2^31
    if (idx >= E * HH) return;
    int e = idx >> 7;
    int c = idx & (HH - 1);
    int s = src[e];
    int d = dst[e];
    float v = dinv[s] * dinv[d] * xw[(size_t)s * HH + c];
    atomAddF(&agg[(size_t)d * HH + c], v);
}

// h = relu(bn(agg + dinv^2*xw + b))   in-place into agg
__global__ void k_post_bn(float* __restrict__ agg, const float* __restrict__ xw,
                          const float* __restrict__ dinv,
                          const float* __restrict__ b, const float* __restrict__ g,
                          const float* __restrict__ beta, const float* __restrict__ m,
                          const float* __restrict__ v, int N) {
    int idx = blockIdx.x * blockDim.x + threadIdx.x;
    if (idx >= N * HH) return;
    int i = idx >> 7;
    int c = idx & (HH - 1);
    float di = dinv[i];
    float val = agg[idx] + di * di * xw[idx] + b[c];
    val = (val - m[c]) * rsqrtf(v[c] + BN_EPS) * g[c] + beta[c];
    agg[idx] = fmaxf(val, 0.0f);
}

// layer-3 epilogue fused with mean-pool partial reduction.
// batch is sorted, so each block (128 consecutive nodes) spans few graphs:
// accumulate in a register, flush one atomic per graph-run.
__global__ __launch_bounds__(128) void k_pool(const float* __restrict__ agg,
                                              const float* __restrict__ xw,
                                              const float* __restrict__ dinv,
                                              const float* __restrict__ b3,
                                              const int* __restrict__ batch,
                                              float* __restrict__ sums, int N) {
    int col = threadIdx.x;
    int n0 = blockIdx.x * 128;
    int n1 = min(n0 + 128, N);
    float bc = b3[col];
    float acc = 0.0f;
    int curg = batch[n0];
    for (int n = n0; n < n1; n++) {
        int gg = batch[n];
        float di = dinv[n];
        float val = agg[(size_t)n * HH + col] + di * di * xw[(size_t)n * HH + col] + bc;
        if (gg != curg) {
            atomAddF(&sums[(size_t)curg * HH + col], acc);
            acc = 0.0f;
            curg = gg;
        }
        acc += val;
    }
    atomAddF(&sums[(size_t)curg * HH + col], acc);
}

__global__ void k_counts(const int* __restrict__ batch, float* __restrict__ counts,
                         int N) {
    int i = blockIdx.x * blockDim.x + threadIdx.x;
    if (i < N) atomAddF(&counts[batch[i]], 1.0f);
}

// per-graph classifier: pooled = sums/counts; z = relu(pooled@Wc1+bc1);
// out = z@Wc2+bc2.  One 64-thread block per graph.
__global__ __launch_bounds__(64) void k_cls(const float* __restrict__ sums,
                                            const float* __restrict__ counts,
                                            const float* __restrict__ Wc1,
                                            const float* __restrict__ bc1,
                                            const float* __restrict__ Wc2,
                                            const float* __restrict__ bc2,
                                            float* __restrict__ out, int Hc, int C) {
    int gI = blockIdx.x;
    int tid = threadIdx.x;
    __shared__ float pooled[HH];
    __shared__ float z[64];
    float cnt = fmaxf(counts[gI], 1.0f);
    for (int c = tid; c < HH; c += 64) pooled[c] = sums[(size_t)gI * HH + c] / cnt;
    __syncthreads();
    if (tid < Hc) {
        float a = bc1[tid];
        for (int k = 0; k < HH; k++) a += pooled[k] * Wc1[k * Hc + tid];
        z[tid] = fmaxf(a, 0.0f);
    }
    __syncthreads();
    if (tid < C) {
        float a = bc2[tid];
        for (int k = 0; k < Hc; k++) a += z[k] * Wc2[k * C + tid];
        out[(size_t)gI * C + tid] = a;
    }
}

extern "C" void kernel_launch(void* const* d_in, const int* in_sizes, int n_in,
                              void* d_out, int out_size, void* d_ws, size_t ws_size,
                              hipStream_t stream) {
    const float* x     = (const float*)d_in[0];
    const int*   ei    = (const int*)d_in[1];
    const int*   batch = (const int*)d_in[2];
    const float* W1    = (const float*)d_in[3];
    const float* b1    = (const float*)d_in[4];
    const float* W2    = (const float*)d_in[5];
    const float* b2    = (const float*)d_in[6];
    const float* W3    = (const float*)d_in[7];
    const float* b3    = (const float*)d_in[8];
    const float* bn1_g = (const float*)d_in[9];
    const float* bn1_b = (const float*)d_in[10];
    const float* bn1_m = (const float*)d_in[11];
    const float* bn1_v = (const float*)d_in[12];
    const float* bn2_g = (const float*)d_in[13];
    const float* bn2_b = (const float*)d_in[14];
    const float* bn2_m = (const float*)d_in[15];
    const float* bn2_v = (const float*)d_in[16];
    const float* Wc1   = (const float*)d_in[17];
    const float* bc1   = (const float*)d_in[18];
    const float* Wc2   = (const float*)d_in[19];
    const float* bc2   = (const float*)d_in[20];
    float* out = (float*)d_out;

    const int N  = in_sizes[2];
    const int E  = in_sizes[1] / 2;
    const int K0 = in_sizes[0] / N;      // D_IN = 256
    const int Hc = in_sizes[18];         // 64
    const int C  = in_sizes[20];         // 16
    const int G  = out_size / C;         // 64

    const int* srcv = ei;
    const int* dstv = ei + E;

    // workspace layout (floats)
    float* ws   = (float*)d_ws;
    size_t NH   = (size_t)N * HH;
    float* dinv = ws;
    float* bufA = ws + (((size_t)N + 255) / 256) * 256;
    float* bufB = bufA + NH;
    float* sums = bufB + NH;             // G*HH, counts right after
    float* cnts = sums + (size_t)G * HH;

    const int T = 256;
    int gN    = (N + T - 1) / T;
    int gE    = (E + T - 1) / T;
    int gNH   = (int)((NH + T - 1) / T);
    int gEHH  = (int)(((size_t)E * HH + T - 1) / T);
    int gGemm = (N + 7) / 8;
    int gPool = (N + 127) / 128;

    // degree -> dinv
    k_fill1<<<gN, T, 0, stream>>>(dinv, N);
    k_deg<<<gE, T, 0, stream>>>(dstv, dinv, E);
    k_rsqrt<<<gN, T, 0, stream>>>(dinv, N);

    // layer 1
    k_gemm<<<gGemm, 128, 0, stream>>>(x, W1, bufA, N, K0);
    hipMemsetAsync(bufB, 0, NH * sizeof(float), stream);
    k_scatter<<<gEHH, T, 0, stream>>>(bufA, dinv, srcv, dstv, bufB, E);
    k_post_bn<<<gNH, T, 0, stream>>>(bufB, bufA, dinv, b1, bn1_g, bn1_b, bn1_m, bn1_v, N);

    // layer 2
    k_gemm<<<gGemm, 128, 0, stream>>>(bufB, W2, bufA, N, HH);
    hipMemsetAsync(bufB, 0, NH * sizeof(float), stream);
    k_scatter<<<gEHH, T, 0, stream>>>(bufA, dinv, srcv, dstv, bufB, E);
    k_post_bn<<<gNH, T, 0, stream>>>(bufB, bufA, dinv, b2, bn2_g, bn2_b, bn2_m, bn2_v, N);

    // layer 3 (+ fused pool)
    k_gemm<<<gGemm, 128, 0, stream>>>(bufB, W3, bufA, N, HH);
    hipMemsetAsync(bufB, 0, NH * sizeof(float), stream);
    k_scatter<<<gEHH, T, 0, stream>>>(bufA, dinv, srcv, dstv, bufB, E);
    hipMemsetAsync(sums, 0, ((size_t)G * HH + G) * sizeof(float), stream);
    k_pool<<<gPool, 128, 0, stream>>>(bufB, bufA, dinv, b3, batch, sums, N);
    k_counts<<<gN, T, 0, stream>>>(batch, cnts, N);

    // classifier head
    k_cls<<<G, 64, 0, stream>>>(sums, cnts, Wc1, bc1, Wc2, bc2, out, Hc, C);
}

// Round 2
// 714.522 us; speedup vs baseline: 2.6419x; 2.6419x over previous
//
#include <hip/hip_runtime.h>

#define HH 128
#define BN_EPS 1e-5f

__device__ inline void atomAddF(float* p, float v) { unsafeAtomicAdd(p, v); }

// ---------- degree / norm ----------
__global__ void k_deg(const int* __restrict__ dst, float* __restrict__ degf, int E) {
    int i = blockIdx.x * blockDim.x + threadIdx.x;
    if (i < E) atomAddF(&degf[dst[i]], 1.0f);
}

__global__ void k_dinv(const float* __restrict__ degf, float* __restrict__ dinv, int n) {
    int i = blockIdx.x * blockDim.x + threadIdx.x;
    if (i < n) dinv[i] = rsqrtf(degf[i] + 1.0f);   // +1 self-loop
}

// ---------- CSR build: scan over integer degrees ----------
__global__ __launch_bounds__(256) void k_scanA(const float* __restrict__ degf,
                                               int* __restrict__ partials, int N) {
    __shared__ int s[256];
    int i = blockIdx.x * 256 + threadIdx.x;
    int d = (i < N) ? (int)degf[i] : 0;
    s[threadIdx.x] = d;
    __syncthreads();
    // block reduce
    for (int off = 128; off > 0; off >>= 1) {
        if (threadIdx.x < off) s[threadIdx.x] += s[threadIdx.x + off];
        __syncthreads();
    }
    if (threadIdx.x == 0) partials[blockIdx.x] = s[0];
}

__global__ __launch_bounds__(256) void k_scanB(int* __restrict__ partials, int nb) {
    __shared__ int s[256];
    int tid = threadIdx.x;
    int v = (tid < nb) ? partials[tid] : 0;
    s[tid] = v;
    __syncthreads();
    for (int off = 1; off < 256; off <<= 1) {
        int t = (tid >= off) ? s[tid - off] : 0;
        __syncthreads();
        s[tid] += t;
        __syncthreads();
    }
    partials[tid] = s[tid] - v;   // exclusive
}

__global__ __launch_bounds__(256) void k_scanC(const float* __restrict__ degf,
                                               const int* __restrict__ partials,
                                               int* __restrict__ rowptr,
                                               int* __restrict__ cursor, int N) {
    __shared__ int s[256];
    int tid = threadIdx.x;
    int i = blockIdx.x * 256 + tid;
    int d = (i < N) ? (int)degf[i] : 0;
    s[tid] = d;
    __syncthreads();
    for (int off = 1; off < 256; off <<= 1) {
        int t = (tid >= off) ? s[tid - off] : 0;
        __syncthreads();
        s[tid] += t;
        __syncthreads();
    }
    int incl = s[tid];
    int base = partials[blockIdx.x];
    if (i < N) {
        rowptr[i] = base + incl - d;
        cursor[i] = base + incl - d;
        if (i == N - 1) rowptr[N] = base + incl;
    }
}

__global__ void k_fill(const int* __restrict__ src, const int* __restrict__ dst,
                       int* __restrict__ cursor, int* __restrict__ csr_src, int E) {
    int e = blockIdx.x * blockDim.x + threadIdx.x;
    if (e < E) {
        int pos = atomicAdd(&cursor[dst[e]], 1);
        csr_src[pos] = src[e];
    }
}

// ---------- GEMM: A[N,K] @ W[K,128] -> out[N,128] ----------
__global__ __launch_bounds__(128) void k_gemm(const float* __restrict__ A,
                                              const float* __restrict__ W,
                                              float* __restrict__ out,
                                              int N, int K) {
    const int R = 16;
    __shared__ __align__(16) float As[R * 256];
    int row0 = blockIdx.x * R;
    int tid = threadIdx.x;
    int K4 = K >> 2;
    const float4* A4 = (const float4*)A;
    float4* As4 = (float4*)As;
    for (int idx = tid; idx < R * K4; idx += 128) {
        int r = idx / K4;
        int kq = idx - r * K4;
        int row = row0 + r;
        As4[idx] = (row < N) ? A4[(size_t)row * K4 + kq]
                             : make_float4(0.f, 0.f, 0.f, 0.f);
    }
    __syncthreads();
    float acc[R];
#pragma unroll
    for (int r = 0; r < R; r++) acc[r] = 0.0f;
#pragma unroll 4
    for (int k = 0; k < K; k++) {
        float wv = W[k * HH + tid];
#pragma unroll
        for (int r = 0; r < R; r++) acc[r] += As[r * K + k] * wv;
    }
#pragma unroll
    for (int r = 0; r < R; r++) {
        int row = row0 + r;
        if (row < N) out[(size_t)row * HH + tid] = acc[r];
    }
}

// ---------- CSR aggregation + fused epilogue ----------
// out[n] = epilogue( dinv[n] * ( sum_{s in N(n)} dinv[s]*xw[s] + dinv[n]*xw[n] ) + b )
// mode 1: BN + ReLU;  mode 0: bias only
__global__ __launch_bounds__(128) void k_agg(const float* __restrict__ xw,
                                             const float* __restrict__ dinv,
                                             const int* __restrict__ rowptr,
                                             const int* __restrict__ csr_src,
                                             const float* __restrict__ b,
                                             const float* __restrict__ g,
                                             const float* __restrict__ beta,
                                             const float* __restrict__ m,
                                             const float* __restrict__ v,
                                             float* __restrict__ out,
                                             int N, int mode) {
    __shared__ int   sS[128];
    __shared__ float sD[128];
    int n = blockIdx.x;
    int col = threadIdx.x;
    int beg = rowptr[n];
    int end = rowptr[n + 1];
    float di = dinv[n];
    float acc = di * xw[(size_t)n * HH + col];     // self-loop (dinv[n]*xw[n])
    for (int base = beg; base < end; base += 128) {
        int cnt = min(128, end - base);
        if (col < cnt) {
            int s = csr_src[base + col];
            sS[col] = s;
            sD[col] = dinv[s];
        }
        __syncthreads();
        for (int j = 0; j < cnt; j++)
            acc += sD[j] * xw[(size_t)sS[j] * HH + col];
        __syncthreads();
    }
    float val = di * acc + b[col];
    if (mode) {
        val = (val - m[col]) * rsqrtf(v[col] + BN_EPS) * g[col] + beta[col];
        val = fmaxf(val, 0.0f);
    }
    out[(size_t)n * HH + col] = val;
}

// ---------- pool (batch sorted: run-based flush) ----------
__global__ __launch_bounds__(128) void k_pool(const float* __restrict__ h,
                                              const int* __restrict__ batch,
                                              float* __restrict__ sums,
                                              float* __restrict__ cnts, int N) {
    int col = threadIdx.x;
    int n0 = blockIdx.x * 128;
    int n1 = min(n0 + 128, N);
    float acc = 0.0f;
    float cnt = 0.0f;
    int curg = batch[n0];
    for (int n = n0; n < n1; n++) {
        int gg = batch[n];
        if (gg != curg) {
            atomAddF(&sums[(size_t)curg * HH + col], acc);
            if (col == 0) atomAddF(&cnts[curg], cnt);
            acc = 0.0f; cnt = 0.0f; curg = gg;
        }
        acc += h[(size_t)n * HH + col];
        cnt += 1.0f;
    }
    atomAddF(&sums[(size_t)curg * HH + col], acc);
    if (col == 0) atomAddF(&cnts[curg], cnt);
}

// ---------- classifier head ----------
__global__ __launch_bounds__(64) void k_cls(const float* __restrict__ sums,
                                            const float* __restrict__ cnts,
                                            const float* __restrict__ Wc1,
                                            const float* __restrict__ bc1,
                                            const float* __restrict__ Wc2,
                                            const float* __restrict__ bc2,
                                            float* __restrict__ out, int Hc, int C) {
    int gI = blockIdx.x;
    int tid = threadIdx.x;
    __shared__ float pooled[HH];
    __shared__ float z[64];
    float cnt = fmaxf(cnts[gI], 1.0f);
    for (int c = tid; c < HH; c += 64) pooled[c] = sums[(size_t)gI * HH + c] / cnt;
    __syncthreads();
    if (tid < Hc) {
        float a = bc1[tid];
        for (int k = 0; k < HH; k++) a += pooled[k] * Wc1[k * Hc + tid];
        z[tid] = fmaxf(a, 0.0f);
    }
    __syncthreads();
    if (tid < C) {
        float a = bc2[tid];
        for (int k = 0; k < Hc; k++) a += z[k] * Wc2[k * C + tid];
        out[(size_t)gI * C + tid] = a;
    }
}

extern "C" void kernel_launch(void* const* d_in, const int* in_sizes, int n_in,
                              void* d_out, int out_size, void* d_ws, size_t ws_size,
                              hipStream_t stream) {
    const float* x     = (const float*)d_in[0];
    const int*   ei    = (const int*)d_in[1];
    const int*   batch = (const int*)d_in[2];
    const float* W1    = (const float*)d_in[3];
    const float* b1    = (const float*)d_in[4];
    const float* W2    = (const float*)d_in[5];
    const float* b2    = (const float*)d_in[6];
    const float* W3    = (const float*)d_in[7];
    const float* b3    = (const float*)d_in[8];
    const float* bn1_g = (const float*)d_in[9];
    const float* bn1_b = (const float*)d_in[10];
    const float* bn1_m = (const float*)d_in[11];
    const float* bn1_v = (const float*)d_in[12];
    const float* bn2_g = (const float*)d_in[13];
    const float* bn2_b = (const float*)d_in[14];
    const float* bn2_m = (const float*)d_in[15];
    const float* bn2_v = (const float*)d_in[16];
    const float* Wc1   = (const float*)d_in[17];
    const float* bc1   = (const float*)d_in[18];
    const float* Wc2   = (const float*)d_in[19];
    const float* bc2   = (const float*)d_in[20];
    float* out = (float*)d_out;

    const int N  = in_sizes[2];
    const int E  = in_sizes[1] / 2;
    const int K0 = in_sizes[0] / N;      // 256
    const int Hc = in_sizes[18];         // 64
    const int C  = in_sizes[20];         // 16
    const int G  = out_size / C;         // 64

    const int* srcv = ei;
    const int* dstv = ei + E;

    // workspace layout (floats; all offsets multiples of 256 -> 1KB aligned)
    float* ws = (float*)d_ws;
    size_t NH = (size_t)N * HH;
    size_t Na = (((size_t)N + 255) / 256) * 256;
    float* bufA    = ws;
    float* bufB    = bufA + NH;
    float* dinv    = bufB + NH;
    float* degf    = dinv + Na;
    int*   rowptr  = (int*)(degf + Na);
    int*   cursor  = rowptr + Na + 256;
    int*   csr_src = cursor + Na;
    int*   partials= csr_src + (((size_t)E + 255) / 256) * 256;
    float* sums    = (float*)(partials + 256);
    float* cnts    = sums + (size_t)G * HH;

    const int T = 256;
    int gN   = (N + T - 1) / T;
    int gE   = (E + T - 1) / T;
    int nb   = gN;                       // 256-sized scan blocks
    int gGemm = (N + 15) / 16;
    int gPool = (N + 127) / 128;

    // degree -> dinv, CSR build
    hipMemsetAsync(degf, 0, N * sizeof(float), stream);
    k_deg<<<gE, T, 0, stream>>>(dstv, degf, E);
    k_dinv<<<gN, T, 0, stream>>>(degf, dinv, N);
    k_scanA<<<nb, 256, 0, stream>>>(degf, partials, N);
    k_scanB<<<1, 256, 0, stream>>>(partials, nb);
    k_scanC<<<nb, 256, 0, stream>>>(degf, partials, rowptr, cursor, N);
    k_fill<<<gE, T, 0, stream>>>(srcv, dstv, cursor, csr_src, E);

    // layer 1: x@W1 -> bufA ; agg+BN+ReLU -> bufB
    k_gemm<<<gGemm, 128, 0, stream>>>(x, W1, bufA, N, K0);
    k_agg<<<N, 128, 0, stream>>>(bufA, dinv, rowptr, csr_src, b1,
                                 bn1_g, bn1_b, bn1_m, bn1_v, bufB, N, 1);
    // layer 2
    k_gemm<<<gGemm, 128, 0, stream>>>(bufB, W2, bufA, N, HH);
    k_agg<<<N, 128, 0, stream>>>(bufA, dinv, rowptr, csr_src, b2,
                                 bn2_g, bn2_b, bn2_m, bn2_v, bufB, N, 1);
    // layer 3 (bias only)
    k_gemm<<<gGemm, 128, 0, stream>>>(bufB, W3, bufA, N, HH);
    k_agg<<<N, 128, 0, stream>>>(bufA, dinv, rowptr, csr_src, b3,
                                 nullptr, nullptr, nullptr, nullptr, bufB, N, 0);

    // pool + classifier
    hipMemsetAsync(sums, 0, ((size_t)G * HH + G) * sizeof(float), stream);
    k_pool<<<gPool, 128, 0, stream>>>(bufB, batch, sums, cnts, N);
    k_cls<<<G, 64, 0, stream>>>(sums, cnts, Wc1, bc1, Wc2, bc2, out, Hc, C);
}

// Round 3
// 596.368 us; speedup vs baseline: 3.1653x; 1.1981x over previous
//
#include <hip/hip_runtime.h>

#define HH 128
#define BN_EPS 1e-5f

typedef __attribute__((ext_vector_type(8))) short short8;
typedef __attribute__((ext_vector_type(4))) float floatx4;

__device__ inline void atomAddF(float* p, float v) { unsafeAtomicAdd(p, v); }

__device__ inline short8 mk8(uint a, uint b, uint c, uint d) {
    union { uint u[4]; short8 s; } t;
    t.u[0] = a; t.u[1] = b; t.u[2] = c; t.u[3] = d;
    return t.s;
}

// ---------- degree / norm ----------
__global__ void k_deg(const int* __restrict__ dst, float* __restrict__ degf, int E) {
    int i = blockIdx.x * blockDim.x + threadIdx.x;
    if (i < E) atomAddF(&degf[dst[i]], 1.0f);
}

__global__ void k_dinv(const float* __restrict__ degf, float* __restrict__ dinv, int n) {
    int i = blockIdx.x * blockDim.x + threadIdx.x;
    if (i < n) dinv[i] = rsqrtf(degf[i] + 1.0f);   // +1 self-loop
}

// ---------- CSR build ----------
__global__ __launch_bounds__(256) void k_scanA(const float* __restrict__ degf,
                                               int* __restrict__ partials, int N) {
    __shared__ int s[256];
    int i = blockIdx.x * 256 + threadIdx.x;
    int d = (i < N) ? (int)degf[i] : 0;
    s[threadIdx.x] = d;
    __syncthreads();
    for (int off = 128; off > 0; off >>= 1) {
        if (threadIdx.x < off) s[threadIdx.x] += s[threadIdx.x + off];
        __syncthreads();
    }
    if (threadIdx.x == 0) partials[blockIdx.x] = s[0];
}

__global__ __launch_bounds__(256) void k_scanB(int* __restrict__ partials, int nb) {
    __shared__ int s[256];
    int tid = threadIdx.x;
    int v = (tid < nb) ? partials[tid] : 0;
    s[tid] = v;
    __syncthreads();
    for (int off = 1; off < 256; off <<= 1) {
        int t = (tid >= off) ? s[tid - off] : 0;
        __syncthreads();
        s[tid] += t;
        __syncthreads();
    }
    partials[tid] = s[tid] - v;   // exclusive
}

__global__ __launch_bounds__(256) void k_scanC(const float* __restrict__ degf,
                                               const int* __restrict__ partials,
                                               int* __restrict__ rowptr,
                                               int* __restrict__ cursor, int N) {
    __shared__ int s[256];
    int tid = threadIdx.x;
    int i = blockIdx.x * 256 + tid;
    int d = (i < N) ? (int)degf[i] : 0;
    s[tid] = d;
    __syncthreads();
    for (int off = 1; off < 256; off <<= 1) {
        int t = (tid >= off) ? s[tid - off] : 0;
        __syncthreads();
        s[tid] += t;
        __syncthreads();
    }
    int incl = s[tid];
    int base = partials[blockIdx.x];
    if (i < N) {
        rowptr[i] = base + incl - d;
        cursor[i] = base + incl - d;
        if (i == N - 1) rowptr[N] = base + incl;
    }
}

__global__ void k_fill(const int* __restrict__ src, const int* __restrict__ dst,
                       int* __restrict__ cursor, int* __restrict__ csr_src, int E) {
    int e = blockIdx.x * blockDim.x + threadIdx.x;
    if (e < E) {
        int pos = atomicAdd(&cursor[dst[e]], 1);
        csr_src[pos] = src[e];
    }
}

// ---------- W split: W[K,128] fp32 -> packed transposed Wp[128][K] words ----------
// word layout along k: for pair (2p,2p+1): word 2p = hi(f1)<<16|hi(f0),
//                                           word 2p+1 = lo(f1)<<16|lo(f0)
__global__ void k_wsplit(const float* __restrict__ W, uint* __restrict__ Wp, int K) {
    int t = blockIdx.x * 256 + threadIdx.x;
    int half = K >> 1;
    if (t >= 128 * half) return;
    int n = t / half;
    int p = t - n * half;
    float f0 = W[(2 * p) * HH + n];
    float f1 = W[(2 * p + 1) * HH + n];
    uint u0 = __float_as_uint(f0), u1 = __float_as_uint(f1);
    uint hw = __builtin_amdgcn_perm(u1, u0, 0x07060302);
    float r0 = f0 - __uint_as_float(u0 & 0xFFFF0000u);
    float r1 = f1 - __uint_as_float(u1 & 0xFFFF0000u);
    uint lw = __builtin_amdgcn_perm(__float_as_uint(r1), __float_as_uint(r0), 0x07060302);
    Wp[n * K + 2 * p]     = hw;
    Wp[n * K + 2 * p + 1] = lw;
}

// ---------- MFMA GEMM: A[N,K] fp32 @ W[K,128] -> out[N,128] fp32 ----------
// split-bf16 (3-term): exact to ~2^-16 relative. A converted in-register.
// Block: 256 thr = 4 waves, 16 rows/wave, 64 rows/block. 8 col-tiles of 16.
__global__ __launch_bounds__(256) void k_gemm_mfma(const float* __restrict__ A,
                                                   const uint* __restrict__ Wp,
                                                   float* __restrict__ out,
                                                   int N, int K) {
    int wave = threadIdx.x >> 6;
    int lane = threadIdx.x & 63;
    int m16  = lane & 15;
    int quad = lane >> 4;
    int row  = blockIdx.x * 64 + wave * 16 + m16;
    int rowc = min(row, N - 1);

    floatx4 acc[8];
#pragma unroll
    for (int c = 0; c < 8; c++) acc[c] = (floatx4){0.f, 0.f, 0.f, 0.f};

    const float* arow = A + (size_t)rowc * K + quad * 8;
    const uint*  bbas = Wp + (size_t)m16 * K + quad * 8;

    for (int kt = 0; kt < K; kt += 32) {
        float4 f0 = *(const float4*)(arow + kt);
        float4 f1 = *(const float4*)(arow + kt + 4);
        uint ahw[4], alw[4];
        {
            uint u0 = __float_as_uint(f0.x), u1 = __float_as_uint(f0.y);
            ahw[0] = __builtin_amdgcn_perm(u1, u0, 0x07060302);
            float r0 = f0.x - __uint_as_float(u0 & 0xFFFF0000u);
            float r1 = f0.y - __uint_as_float(u1 & 0xFFFF0000u);
            alw[0] = __builtin_amdgcn_perm(__float_as_uint(r1), __float_as_uint(r0), 0x07060302);
            u0 = __float_as_uint(f0.z); u1 = __float_as_uint(f0.w);
            ahw[1] = __builtin_amdgcn_perm(u1, u0, 0x07060302);
            r0 = f0.z - __uint_as_float(u0 & 0xFFFF0000u);
            r1 = f0.w - __uint_as_float(u1 & 0xFFFF0000u);
            alw[1] = __builtin_amdgcn_perm(__float_as_uint(r1), __float_as_uint(r0), 0x07060302);
            u0 = __float_as_uint(f1.x); u1 = __float_as_uint(f1.y);
            ahw[2] = __builtin_amdgcn_perm(u1, u0, 0x07060302);
            r0 = f1.x - __uint_as_float(u0 & 0xFFFF0000u);
            r1 = f1.y - __uint_as_float(u1 & 0xFFFF0000u);
            alw[2] = __builtin_amdgcn_perm(__float_as_uint(r1), __float_as_uint(r0), 0x07060302);
            u0 = __float_as_uint(f1.z); u1 = __float_as_uint(f1.w);
            ahw[3] = __builtin_amdgcn_perm(u1, u0, 0x07060302);
            r0 = f1.z - __uint_as_float(u0 & 0xFFFF0000u);
            r1 = f1.w - __uint_as_float(u1 & 0xFFFF0000u);
            alw[3] = __builtin_amdgcn_perm(__float_as_uint(r1), __float_as_uint(r0), 0x07060302);
        }
        short8 a_hi = mk8(ahw[0], ahw[1], ahw[2], ahw[3]);
        short8 a_lo = mk8(alw[0], alw[1], alw[2], alw[3]);

#pragma unroll
        for (int c = 0; c < 8; c++) {
            const uint* bp = bbas + (size_t)c * 16 * K + kt;
            uint4 w0 = *(const uint4*)(bp);
            uint4 w1 = *(const uint4*)(bp + 4);
            short8 b_hi = mk8(w0.x, w0.z, w1.x, w1.z);
            short8 b_lo = mk8(w0.y, w0.w, w1.y, w1.w);
            acc[c] = __builtin_amdgcn_mfma_f32_16x16x32_bf16(a_hi, b_hi, acc[c], 0, 0, 0);
            acc[c] = __builtin_amdgcn_mfma_f32_16x16x32_bf16(a_lo, b_hi, acc[c], 0, 0, 0);
            acc[c] = __builtin_amdgcn_mfma_f32_16x16x32_bf16(a_hi, b_lo, acc[c], 0, 0, 0);
        }
    }

    int rowbase = blockIdx.x * 64 + wave * 16 + quad * 4;
#pragma unroll
    for (int c = 0; c < 8; c++) {
#pragma unroll
        for (int r = 0; r < 4; r++) {
            int rr = rowbase + r;
            if (rr < N) out[(size_t)rr * HH + c * 16 + m16] = acc[c][r];
        }
    }
}

// ---------- CSR aggregation + fused epilogue ----------
__global__ __launch_bounds__(128) void k_agg(const float* __restrict__ xw,
                                             const float* __restrict__ dinv,
                                             const int* __restrict__ rowptr,
                                             const int* __restrict__ csr_src,
                                             const float* __restrict__ b,
                                             const float* __restrict__ g,
                                             const float* __restrict__ beta,
                                             const float* __restrict__ m,
                                             const float* __restrict__ v,
                                             float* __restrict__ out,
                                             int N, int mode) {
    __shared__ int   sS[128];
    __shared__ float sD[128];
    int n = blockIdx.x;
    int col = threadIdx.x;
    int beg = rowptr[n];
    int end = rowptr[n + 1];
    float di = dinv[n];
    float acc = di * xw[(size_t)n * HH + col];     // self-loop
    for (int base = beg; base < end; base += 128) {
        int cnt = min(128, end - base);
        if (col < cnt) {
            int s = csr_src[base + col];
            sS[col] = s;
            sD[col] = dinv[s];
        }
        __syncthreads();
        for (int j = 0; j < cnt; j++)
            acc += sD[j] * xw[(size_t)sS[j] * HH + col];
        __syncthreads();
    }
    float val = di * acc + b[col];
    if (mode) {
        val = (val - m[col]) * rsqrtf(v[col] + BN_EPS) * g[col] + beta[col];
        val = fmaxf(val, 0.0f);
    }
    out[(size_t)n * HH + col] = val;
}

// ---------- pool ----------
__global__ __launch_bounds__(128) void k_pool(const float* __restrict__ h,
                                              const int* __restrict__ batch,
                                              float* __restrict__ sums,
                                              float* __restrict__ cnts, int N) {
    int col = threadIdx.x;
    int n0 = blockIdx.x * 128;
    int n1 = min(n0 + 128, N);
    float acc = 0.0f;
    float cnt = 0.0f;
    int curg = batch[n0];
    for (int n = n0; n < n1; n++) {
        int gg = batch[n];
        if (gg != curg) {
            atomAddF(&sums[(size_t)curg * HH + col], acc);
            if (col == 0) atomAddF(&cnts[curg], cnt);
            acc = 0.0f; cnt = 0.0f; curg = gg;
        }
        acc += h[(size_t)n * HH + col];
        cnt += 1.0f;
    }
    atomAddF(&sums[(size_t)curg * HH + col], acc);
    if (col == 0) atomAddF(&cnts[curg], cnt);
}

// ---------- classifier head ----------
__global__ __launch_bounds__(64) void k_cls(const float* __restrict__ sums,
                                            const float* __restrict__ cnts,
                                            const float* __restrict__ Wc1,
                                            const float* __restrict__ bc1,
                                            const float* __restrict__ Wc2,
                                            const float* __restrict__ bc2,
                                            float* __restrict__ out, int Hc, int C) {
    int gI = blockIdx.x;
    int tid = threadIdx.x;
    __shared__ float pooled[HH];
    __shared__ float z[64];
    float cnt = fmaxf(cnts[gI], 1.0f);
    for (int c = tid; c < HH; c += 64) pooled[c] = sums[(size_t)gI * HH + c] / cnt;
    __syncthreads();
    if (tid < Hc) {
        float a = bc1[tid];
        for (int k = 0; k < HH; k++) a += pooled[k] * Wc1[k * Hc + tid];
        z[tid] = fmaxf(a, 0.0f);
    }
    __syncthreads();
    if (tid < C) {
        float a = bc2[tid];
        for (int k = 0; k < Hc; k++) a += z[k] * Wc2[k * C + tid];
        out[(size_t)gI * C + tid] = a;
    }
}

extern "C" void kernel_launch(void* const* d_in, const int* in_sizes, int n_in,
                              void* d_out, int out_size, void* d_ws, size_t ws_size,
                              hipStream_t stream) {
    const float* x     = (const float*)d_in[0];
    const int*   ei    = (const int*)d_in[1];
    const int*   batch = (const int*)d_in[2];
    const float* W1    = (const float*)d_in[3];
    const float* b1    = (const float*)d_in[4];
    const float* W2    = (const float*)d_in[5];
    const float* b2    = (const float*)d_in[6];
    const float* W3    = (const float*)d_in[7];
    const float* b3    = (const float*)d_in[8];
    const float* bn1_g = (const float*)d_in[9];
    const float* bn1_b = (const float*)d_in[10];
    const float* bn1_m = (const float*)d_in[11];
    const float* bn1_v = (const float*)d_in[12];
    const float* bn2_g = (const float*)d_in[13];
    const float* bn2_b = (const float*)d_in[14];
    const float* bn2_m = (const float*)d_in[15];
    const float* bn2_v = (const float*)d_in[16];
    const float* Wc1   = (const float*)d_in[17];
    const float* bc1   = (const float*)d_in[18];
    const float* Wc2   = (const float*)d_in[19];
    const float* bc2   = (const float*)d_in[20];
    float* out = (float*)d_out;

    const int N  = in_sizes[2];
    const int E  = in_sizes[1] / 2;
    const int K0 = in_sizes[0] / N;      // 256
    const int Hc = in_sizes[18];         // 64
    const int C  = in_sizes[20];         // 16
    const int G  = out_size / C;         // 64

    const int* srcv = ei;
    const int* dstv = ei + E;

    // workspace layout
    float* ws = (float*)d_ws;
    size_t NH = (size_t)N * HH;
    size_t Na = (((size_t)N + 255) / 256) * 256;
    float* bufA    = ws;
    float* bufB    = bufA + NH;
    float* dinv    = bufB + NH;
    float* degf    = dinv + Na;
    int*   rowptr  = (int*)(degf + Na);
    int*   cursor  = rowptr + Na + 256;
    int*   csr_src = cursor + Na;
    int*   partials= csr_src + (((size_t)E + 255) / 256) * 256;
    float* sums    = (float*)(partials + 256);
    float* cnts    = sums + (size_t)G * HH;
    uint*  Wp1     = (uint*)(cnts + 256);          // K0*128 words
    uint*  Wp2     = Wp1 + (size_t)K0 * HH;
    uint*  Wp3     = Wp2 + (size_t)HH * HH;

    const int T = 256;
    int gN   = (N + T - 1) / T;
    int gE   = (E + T - 1) / T;
    int nb   = gN;
    int gGemm = (N + 63) / 64;
    int gPool = (N + 127) / 128;

    // degree -> dinv, CSR build
    hipMemsetAsync(degf, 0, N * sizeof(float), stream);
    k_deg<<<gE, T, 0, stream>>>(dstv, degf, E);
    k_dinv<<<gN, T, 0, stream>>>(degf, dinv, N);
    k_scanA<<<nb, 256, 0, stream>>>(degf, partials, N);
    k_scanB<<<1, 256, 0, stream>>>(partials, nb);
    k_scanC<<<nb, 256, 0, stream>>>(degf, partials, rowptr, cursor, N);
    k_fill<<<gE, T, 0, stream>>>(srcv, dstv, cursor, csr_src, E);

    // weight splits (tiny)
    k_wsplit<<<(128 * (K0 / 2) + 255) / 256, 256, 0, stream>>>(W1, Wp1, K0);
    k_wsplit<<<(128 * (HH / 2) + 255) / 256, 256, 0, stream>>>(W2, Wp2, HH);
    k_wsplit<<<(128 * (HH / 2) + 255) / 256, 256, 0, stream>>>(W3, Wp3, HH);

    // layer 1
    k_gemm_mfma<<<gGemm, 256, 0, stream>>>(x, Wp1, bufA, N, K0);
    k_agg<<<N, 128, 0, stream>>>(bufA, dinv, rowptr, csr_src, b1,
                                 bn1_g, bn1_b, bn1_m, bn1_v, bufB, N, 1);
    // layer 2
    k_gemm_mfma<<<gGemm, 256, 0, stream>>>(bufB, Wp2, bufA, N, HH);
    k_agg<<<N, 128, 0, stream>>>(bufA, dinv, rowptr, csr_src, b2,
                                 bn2_g, bn2_b, bn2_m, bn2_v, bufB, N, 1);
    // layer 3
    k_gemm_mfma<<<gGemm, 256, 0, stream>>>(bufB, Wp3, bufA, N, HH);
    k_agg<<<N, 128, 0, stream>>>(bufA, dinv, rowptr, csr_src, b3,
                                 nullptr, nullptr, nullptr, nullptr, bufB, N, 0);

    // pool + classifier
    hipMemsetAsync(sums, 0, ((size_t)G * HH + G) * sizeof(float), stream);
    k_pool<<<gPool, 128, 0, stream>>>(bufB, batch, sums, cnts, N);
    k_cls<<<G, 64, 0, stream>>>(sums, cnts, Wc1, bc1, Wc2, bc2, out, Hc, C);
}

// Round 4
// 589.868 us; speedup vs baseline: 3.2002x; 1.0110x over previous
//
#include <hip/hip_runtime.h>

#define HH 128
#define BN_EPS 1e-5f

typedef __attribute__((ext_vector_type(8))) short short8;
typedef __attribute__((ext_vector_type(4))) float floatx4;

__device__ inline void atomAddF(float* p, float v) { unsafeAtomicAdd(p, v); }

__device__ inline short8 mk8(uint a, uint b, uint c, uint d) {
    union { uint u[4]; short8 s; } t;
    t.u[0] = a; t.u[1] = b; t.u[2] = c; t.u[3] = d;
    return t.s;
}

// split one float pair into hi-word / lo-word (bf16x2 each)
__device__ inline void splitPair(float f0, float f1, uint& hw, uint& lw) {
    uint u0 = __float_as_uint(f0), u1 = __float_as_uint(f1);
    hw = __builtin_amdgcn_perm(u1, u0, 0x07060302);
    float r0 = f0 - __uint_as_float(u0 & 0xFFFF0000u);
    float r1 = f1 - __uint_as_float(u1 & 0xFFFF0000u);
    lw = __builtin_amdgcn_perm(__float_as_uint(r1), __float_as_uint(r0), 0x07060302);
}

// ---------- degree / norm ----------
__global__ void k_deg(const int* __restrict__ dst, float* __restrict__ degf, int E) {
    int i = blockIdx.x * blockDim.x + threadIdx.x;
    if (i < E) atomAddF(&degf[dst[i]], 1.0f);
}

__global__ void k_dinv(const float* __restrict__ degf, float* __restrict__ dinv, int n) {
    int i = blockIdx.x * blockDim.x + threadIdx.x;
    if (i < n) dinv[i] = rsqrtf(degf[i] + 1.0f);   // +1 self-loop
}

// ---------- CSR build ----------
__global__ __launch_bounds__(256) void k_scanA(const float* __restrict__ degf,
                                               int* __restrict__ partials, int N) {
    __shared__ int s[256];
    int i = blockIdx.x * 256 + threadIdx.x;
    int d = (i < N) ? (int)degf[i] : 0;
    s[threadIdx.x] = d;
    __syncthreads();
    for (int off = 128; off > 0; off >>= 1) {
        if (threadIdx.x < off) s[threadIdx.x] += s[threadIdx.x + off];
        __syncthreads();
    }
    if (threadIdx.x == 0) partials[blockIdx.x] = s[0];
}

__global__ __launch_bounds__(256) void k_scanB(int* __restrict__ partials, int nb) {
    __shared__ int s[256];
    int tid = threadIdx.x;
    int v = (tid < nb) ? partials[tid] : 0;
    s[tid] = v;
    __syncthreads();
    for (int off = 1; off < 256; off <<= 1) {
        int t = (tid >= off) ? s[tid - off] : 0;
        __syncthreads();
        s[tid] += t;
        __syncthreads();
    }
    partials[tid] = s[tid] - v;   // exclusive
}

__global__ __launch_bounds__(256) void k_scanC(const float* __restrict__ degf,
                                               const int* __restrict__ partials,
                                               int* __restrict__ rowptr,
                                               int* __restrict__ cursor, int N) {
    __shared__ int s[256];
    int tid = threadIdx.x;
    int i = blockIdx.x * 256 + tid;
    int d = (i < N) ? (int)degf[i] : 0;
    s[tid] = d;
    __syncthreads();
    for (int off = 1; off < 256; off <<= 1) {
        int t = (tid >= off) ? s[tid - off] : 0;
        __syncthreads();
        s[tid] += t;
        __syncthreads();
    }
    int incl = s[tid];
    int base = partials[blockIdx.x];
    if (i < N) {
        rowptr[i] = base + incl - d;
        cursor[i] = base + incl - d;
        if (i == N - 1) rowptr[N] = base + incl;
    }
}

__global__ void k_fill(const int* __restrict__ src, const int* __restrict__ dst,
                       int* __restrict__ cursor, int* __restrict__ csr_src, int E) {
    int e = blockIdx.x * blockDim.x + threadIdx.x;
    if (e < E) {
        int pos = atomicAdd(&cursor[dst[e]], 1);
        csr_src[pos] = src[e];
    }
}

// ---------- W split: W[K,128] -> packed transposed Wp[128][K] words ----------
__global__ void k_wsplit(const float* __restrict__ W, uint* __restrict__ Wp, int K) {
    int t = blockIdx.x * 256 + threadIdx.x;
    int half = K >> 1;
    if (t >= 128 * half) return;
    int n = t / half;
    int p = t - n * half;
    uint hw, lw;
    splitPair(W[(2 * p) * HH + n], W[(2 * p + 1) * HH + n], hw, lw);
    Wp[n * K + 2 * p]     = hw;
    Wp[n * K + 2 * p + 1] = lw;
}

// ---------- MFMA GEMM: A[N,K] fp32 @ W[K,128] -> out[N,128] fp32 ----------
// Full-row A prefetch (all K loads issued up front -> HBM BW, not latency).
// 16 rows/wave, 64 rows/block, 8 col-tiles, split-bf16 3-term.
template<int KT>   // K = KT*32
__global__ __launch_bounds__(256) void k_gemm_mfma(const float* __restrict__ A,
                                                   const uint* __restrict__ Wp,
                                                   float* __restrict__ out,
                                                   int N) {
    const int K = KT * 32;
    int wave = threadIdx.x >> 6;
    int lane = threadIdx.x & 63;
    int m16  = lane & 15;
    int quad = lane >> 4;
    int row  = blockIdx.x * 64 + wave * 16 + m16;
    int rowc = min(row, N - 1);

    // prefetch the whole A row-fragment: 2 float4 per kt
    const float4* a4 = (const float4*)(A + (size_t)rowc * K);
    float4 araw[2 * KT];
#pragma unroll
    for (int kt = 0; kt < KT; kt++) {
        araw[2 * kt]     = a4[kt * 8 + quad * 2];
        araw[2 * kt + 1] = a4[kt * 8 + quad * 2 + 1];
    }

    floatx4 acc[8];
#pragma unroll
    for (int c = 0; c < 8; c++) acc[c] = (floatx4){0.f, 0.f, 0.f, 0.f};

    const uint* bbas = Wp + (size_t)m16 * K + quad * 8;

#pragma unroll
    for (int kt = 0; kt < KT; kt++) {
        float4 f0 = araw[2 * kt];
        float4 f1 = araw[2 * kt + 1];
        uint ahw[4], alw[4];
        splitPair(f0.x, f0.y, ahw[0], alw[0]);
        splitPair(f0.z, f0.w, ahw[1], alw[1]);
        splitPair(f1.x, f1.y, ahw[2], alw[2]);
        splitPair(f1.z, f1.w, ahw[3], alw[3]);
        short8 a_hi = mk8(ahw[0], ahw[1], ahw[2], ahw[3]);
        short8 a_lo = mk8(alw[0], alw[1], alw[2], alw[3]);

#pragma unroll
        for (int c = 0; c < 8; c++) {
            const uint* bp = bbas + (size_t)c * 16 * K + kt * 32;
            uint4 w0 = *(const uint4*)(bp);
            uint4 w1 = *(const uint4*)(bp + 4);
            short8 b_hi = mk8(w0.x, w0.z, w1.x, w1.z);
            short8 b_lo = mk8(w0.y, w0.w, w1.y, w1.w);
            acc[c] = __builtin_amdgcn_mfma_f32_16x16x32_bf16(a_hi, b_hi, acc[c], 0, 0, 0);
            acc[c] = __builtin_amdgcn_mfma_f32_16x16x32_bf16(a_lo, b_hi, acc[c], 0, 0, 0);
            acc[c] = __builtin_amdgcn_mfma_f32_16x16x32_bf16(a_hi, b_lo, acc[c], 0, 0, 0);
        }
    }

    int rowbase = blockIdx.x * 64 + wave * 16 + quad * 4;
#pragma unroll
    for (int c = 0; c < 8; c++) {
#pragma unroll
        for (int r = 0; r < 4; r++) {
            int rr = rowbase + r;
            if (rr < N) out[(size_t)rr * HH + c * 16 + m16] = acc[c][r];
        }
    }
}

// ---------- CSR aggregation + fused epilogue ----------
// wave-per-node, float2/lane, wave-private LDS staging (no barriers)
__global__ __launch_bounds__(256) void k_agg(const float* __restrict__ xw,
                                             const float* __restrict__ dinv,
                                             const int* __restrict__ rowptr,
                                             const int* __restrict__ csr_src,
                                             const float* __restrict__ b,
                                             const float* __restrict__ g,
                                             const float* __restrict__ beta,
                                             const float* __restrict__ m,
                                             const float* __restrict__ v,
                                             float* __restrict__ out,
                                             int N, int mode) {
    __shared__ int   sS[256];
    __shared__ float sD[256];
    int wave = threadIdx.x >> 6;
    int lane = threadIdx.x & 63;
    int n = blockIdx.x * 4 + wave;
    if (n >= N) return;
    int wbase = wave * 64;

    int beg = rowptr[n];
    int end = rowptr[n + 1];
    float di = dinv[n];
    const float2* xw2 = (const float2*)xw;

    float2 self = xw2[(size_t)n * 64 + lane];
    float accx = di * self.x;
    float accy = di * self.y;

    for (int base = beg; base < end; base += 64) {
        int cnt = min(64, end - base);
        if (lane < cnt) {
            int s = csr_src[base + lane];
            sS[wbase + lane] = s;
            sD[wbase + lane] = dinv[s];
        }
        // same-wave LDS write->read: compiler inserts lgkmcnt wait; no barrier needed
#pragma unroll 4
        for (int j = 0; j < cnt; j++) {
            int sj  = sS[wbase + j];
            float dj = sD[wbase + j];
            float2 r = xw2[(size_t)sj * 64 + lane];
            accx = fmaf(dj, r.x, accx);
            accy = fmaf(dj, r.y, accy);
        }
    }

    float2 bb = ((const float2*)b)[lane];
    float vx = di * accx + bb.x;
    float vy = di * accy + bb.y;
    if (mode) {
        float2 mm = ((const float2*)m)[lane];
        float2 vv = ((const float2*)v)[lane];
        float2 gg = ((const float2*)g)[lane];
        float2 be = ((const float2*)beta)[lane];
        vx = (vx - mm.x) * rsqrtf(vv.x + BN_EPS) * gg.x + be.x;
        vy = (vy - mm.y) * rsqrtf(vv.y + BN_EPS) * gg.y + be.y;
        vx = fmaxf(vx, 0.0f);
        vy = fmaxf(vy, 0.0f);
    }
    ((float2*)out)[(size_t)n * 64 + lane] = make_float2(vx, vy);
}

// ---------- pool ----------
__global__ __launch_bounds__(128) void k_pool(const float* __restrict__ h,
                                              const int* __restrict__ batch,
                                              float* __restrict__ sums,
                                              float* __restrict__ cnts, int N) {
    int col = threadIdx.x;
    int n0 = blockIdx.x * 128;
    int n1 = min(n0 + 128, N);
    float acc = 0.0f;
    float cnt = 0.0f;
    int curg = batch[n0];
    for (int n = n0; n < n1; n++) {
        int gg = batch[n];
        if (gg != curg) {
            atomAddF(&sums[(size_t)curg * HH + col], acc);
            if (col == 0) atomAddF(&cnts[curg], cnt);
            acc = 0.0f; cnt = 0.0f; curg = gg;
        }
        acc += h[(size_t)n * HH + col];
        cnt += 1.0f;
    }
    atomAddF(&sums[(size_t)curg * HH + col], acc);
    if (col == 0) atomAddF(&cnts[curg], cnt);
}

// ---------- classifier head ----------
__global__ __launch_bounds__(64) void k_cls(const float* __restrict__ sums,
                                            const float* __restrict__ cnts,
                                            const float* __restrict__ Wc1,
                                            const float* __restrict__ bc1,
                                            const float* __restrict__ Wc2,
                                            const float* __restrict__ bc2,
                                            float* __restrict__ out, int Hc, int C) {
    int gI = blockIdx.x;
    int tid = threadIdx.x;
    __shared__ float pooled[HH];
    __shared__ float z[64];
    float cnt = fmaxf(cnts[gI], 1.0f);
    for (int c = tid; c < HH; c += 64) pooled[c] = sums[(size_t)gI * HH + c] / cnt;
    __syncthreads();
    if (tid < Hc) {
        float a = bc1[tid];
        for (int k = 0; k < HH; k++) a += pooled[k] * Wc1[k * Hc + tid];
        z[tid] = fmaxf(a, 0.0f);
    }
    __syncthreads();
    if (tid < C) {
        float a = bc2[tid];
        for (int k = 0; k < Hc; k++) a += z[k] * Wc2[k * C + tid];
        out[(size_t)gI * C + tid] = a;
    }
}

extern "C" void kernel_launch(void* const* d_in, const int* in_sizes, int n_in,
                              void* d_out, int out_size, void* d_ws, size_t ws_size,
                              hipStream_t stream) {
    const float* x     = (const float*)d_in[0];
    const int*   ei    = (const int*)d_in[1];
    const int*   batch = (const int*)d_in[2];
    const float* W1    = (const float*)d_in[3];
    const float* b1    = (const float*)d_in[4];
    const float* W2    = (const float*)d_in[5];
    const float* b2    = (const float*)d_in[6];
    const float* W3    = (const float*)d_in[7];
    const float* b3    = (const float*)d_in[8];
    const float* bn1_g = (const float*)d_in[9];
    const float* bn1_b = (const float*)d_in[10];
    const float* bn1_m = (const float*)d_in[11];
    const float* bn1_v = (const float*)d_in[12];
    const float* bn2_g = (const float*)d_in[13];
    const float* bn2_b = (const float*)d_in[14];
    const float* bn2_m = (const float*)d_in[15];
    const float* bn2_v = (const float*)d_in[16];
    const float* Wc1   = (const float*)d_in[17];
    const float* bc1   = (const float*)d_in[18];
    const float* Wc2   = (const float*)d_in[19];
    const float* bc2   = (const float*)d_in[20];
    float* out = (float*)d_out;

    const int N  = in_sizes[2];
    const int E  = in_sizes[1] / 2;
    const int K0 = in_sizes[0] / N;      // 256
    const int Hc = in_sizes[18];         // 64
    const int C  = in_sizes[20];         // 16
    const int G  = out_size / C;         // 64

    const int* srcv = ei;
    const int* dstv = ei + E;

    // workspace layout
    float* ws = (float*)d_ws;
    size_t NH = (size_t)N * HH;
    size_t Na = (((size_t)N + 255) / 256) * 256;
    float* bufA    = ws;
    float* bufB    = bufA + NH;
    float* dinv    = bufB + NH;
    float* degf    = dinv + Na;
    int*   rowptr  = (int*)(degf + Na);
    int*   cursor  = rowptr + Na + 256;
    int*   csr_src = cursor + Na;
    int*   partials= csr_src + (((size_t)E + 255) / 256) * 256;
    float* sums    = (float*)(partials + 256);
    float* cnts    = sums + (size_t)G * HH;
    uint*  Wp1     = (uint*)(cnts + 256);
    uint*  Wp2     = Wp1 + (size_t)K0 * HH;
    uint*  Wp3     = Wp2 + (size_t)HH * HH;

    const int T = 256;
    int gN   = (N + T - 1) / T;
    int gE   = (E + T - 1) / T;
    int nb   = gN;
    int gGemm = (N + 63) / 64;
    int gAgg  = (N + 3) / 4;
    int gPool = (N + 127) / 128;

    // degree -> dinv, CSR build
    hipMemsetAsync(degf, 0, N * sizeof(float), stream);
    k_deg<<<gE, T, 0, stream>>>(dstv, degf, E);
    k_dinv<<<gN, T, 0, stream>>>(degf, dinv, N);
    k_scanA<<<nb, 256, 0, stream>>>(degf, partials, N);
    k_scanB<<<1, 256, 0, stream>>>(partials, nb);
    k_scanC<<<nb, 256, 0, stream>>>(degf, partials, rowptr, cursor, N);
    k_fill<<<gE, T, 0, stream>>>(srcv, dstv, cursor, csr_src, E);

    // weight splits
    k_wsplit<<<(128 * (K0 / 2) + 255) / 256, 256, 0, stream>>>(W1, Wp1, K0);
    k_wsplit<<<(128 * (HH / 2) + 255) / 256, 256, 0, stream>>>(W2, Wp2, HH);
    k_wsplit<<<(128 * (HH / 2) + 255) / 256, 256, 0, stream>>>(W3, Wp3, HH);

    // layer 1
    if (K0 == 256)
        k_gemm_mfma<8><<<gGemm, 256, 0, stream>>>(x, Wp1, bufA, N);
    else
        k_gemm_mfma<4><<<gGemm, 256, 0, stream>>>(x, Wp1, bufA, N);
    k_agg<<<gAgg, 256, 0, stream>>>(bufA, dinv, rowptr, csr_src, b1,
                                    bn1_g, bn1_b, bn1_m, bn1_v, bufB, N, 1);
    // layer 2
    k_gemm_mfma<4><<<gGemm, 256, 0, stream>>>(bufB, Wp2, bufA, N);
    k_agg<<<gAgg, 256, 0, stream>>>(bufA, dinv, rowptr, csr_src, b2,
                                    bn2_g, bn2_b, bn2_m, bn2_v, bufB, N, 1);
    // layer 3
    k_gemm_mfma<4><<<gGemm, 256, 0, stream>>>(bufB, Wp3, bufA, N);
    k_agg<<<gAgg, 256, 0, stream>>>(bufA, dinv, rowptr, csr_src, b3,
                                    nullptr, nullptr, nullptr, nullptr, bufB, N, 0);

    // pool + classifier
    hipMemsetAsync(sums, 0, ((size_t)G * HH + G) * sizeof(float), stream);
    k_pool<<<gPool, 128, 0, stream>>>(bufB, batch, sums, cnts, N);
    k_cls<<<G, 64, 0, stream>>>(sums, cnts, Wc1, bc1, Wc2, bc2, out, Hc, C);
}

// Round 5
// 493.214 us; speedup vs baseline: 3.8273x; 1.1960x over previous
//
#include <hip/hip_runtime.h>

#define HH 128
#define BN_EPS 1e-5f

typedef __attribute__((ext_vector_type(8))) short short8;
typedef __attribute__((ext_vector_type(4))) float floatx4;

__device__ inline void atomAddF(float* p, float v) { unsafeAtomicAdd(p, v); }

__device__ inline short8 mk8(uint a, uint b, uint c, uint d) {
    union { uint u[4]; short8 s; } t;
    t.u[0] = a; t.u[1] = b; t.u[2] = c; t.u[3] = d;
    return t.s;
}

// split one float pair into hi-word / lo-word (bf16x2 each)
__device__ inline void splitPair(float f0, float f1, uint& hw, uint& lw) {
    uint u0 = __float_as_uint(f0), u1 = __float_as_uint(f1);
    hw = __builtin_amdgcn_perm(u1, u0, 0x07060302);
    float r0 = f0 - __uint_as_float(u0 & 0xFFFF0000u);
    float r1 = f1 - __uint_as_float(u1 & 0xFFFF0000u);
    lw = __builtin_amdgcn_perm(__float_as_uint(r1), __float_as_uint(r0), 0x07060302);
}

// ---------- degree / norm ----------
__global__ void k_deg(const int* __restrict__ dst, float* __restrict__ degf, int E) {
    int i = blockIdx.x * blockDim.x + threadIdx.x;
    if (i < E) atomAddF(&degf[dst[i]], 1.0f);
}

__global__ void k_dinv(const float* __restrict__ degf, float* __restrict__ dinv, int n) {
    int i = blockIdx.x * blockDim.x + threadIdx.x;
    if (i < n) dinv[i] = rsqrtf(degf[i] + 1.0f);   // +1 self-loop
}

// ---------- CSR build ----------
__global__ __launch_bounds__(256) void k_scanA(const float* __restrict__ degf,
                                               int* __restrict__ partials, int N) {
    __shared__ int s[256];
    int i = blockIdx.x * 256 + threadIdx.x;
    int d = (i < N) ? (int)degf[i] : 0;
    s[threadIdx.x] = d;
    __syncthreads();
    for (int off = 128; off > 0; off >>= 1) {
        if (threadIdx.x < off) s[threadIdx.x] += s[threadIdx.x + off];
        __syncthreads();
    }
    if (threadIdx.x == 0) partials[blockIdx.x] = s[0];
}

__global__ __launch_bounds__(256) void k_scanB(int* __restrict__ partials, int nb) {
    __shared__ int s[256];
    int tid = threadIdx.x;
    int v = (tid < nb) ? partials[tid] : 0;
    s[tid] = v;
    __syncthreads();
    for (int off = 1; off < 256; off <<= 1) {
        int t = (tid >= off) ? s[tid - off] : 0;
        __syncthreads();
        s[tid] += t;
        __syncthreads();
    }
    partials[tid] = s[tid] - v;   // exclusive
}

__global__ __launch_bounds__(256) void k_scanC(const float* __restrict__ degf,
                                               const int* __restrict__ partials,
                                               int* __restrict__ rowptr,
                                               int* __restrict__ cursor, int N) {
    __shared__ int s[256];
    int tid = threadIdx.x;
    int i = blockIdx.x * 256 + tid;
    int d = (i < N) ? (int)degf[i] : 0;
    s[tid] = d;
    __syncthreads();
    for (int off = 1; off < 256; off <<= 1) {
        int t = (tid >= off) ? s[tid - off] : 0;
        __syncthreads();
        s[tid] += t;
        __syncthreads();
    }
    int incl = s[tid];
    int base = partials[blockIdx.x];
    if (i < N) {
        rowptr[i] = base + incl - d;
        cursor[i] = base + incl - d;
        if (i == N - 1) rowptr[N] = base + incl;
    }
}

__global__ void k_fill(const int* __restrict__ src, const int* __restrict__ dst,
                       int* __restrict__ cursor, int* __restrict__ csr_src, int E) {
    int e = blockIdx.x * blockDim.x + threadIdx.x;
    if (e < E) {
        int pos = atomicAdd(&cursor[dst[e]], 1);
        csr_src[pos] = src[e];
    }
}

// ---------- W split: W[K,128] -> packed transposed Wp[128][K] words ----------
__global__ void k_wsplit(const float* __restrict__ W, uint* __restrict__ Wp, int K) {
    int t = blockIdx.x * 256 + threadIdx.x;
    int half = K >> 1;
    if (t >= 128 * half) return;
    int n = t / half;
    int p = t - n * half;
    uint hw, lw;
    splitPair(W[(2 * p) * HH + n], W[(2 * p + 1) * HH + n], hw, lw);
    Wp[n * K + 2 * p]     = hw;
    Wp[n * K + 2 * p + 1] = lw;
}

// ---------- MFMA GEMM: A[N,K] fp32 @ W[K,128] -> out[N,128] fp32 ----------
// B staged in LDS per 64-word K-chunk (coalesced, deep-in-flight);
// inner loop = ds_read_b128 + MFMA. A row-fragment prefetched to VGPRs.
// Block: 256 thr = 4 waves, 64 rows, 128 cols. split-bf16 3-term.
template<int KT>   // K = KT*32 elements (== KT*32 packed words)
__global__ __launch_bounds__(256) void k_gemm_mfma(const float* __restrict__ A,
                                                   const uint* __restrict__ Wp,
                                                   float* __restrict__ out,
                                                   int N) {
    const int K = KT * 32;
    const int NCH = KT / 2;                 // 64-word chunks
    __shared__ uint Bs[128 * 68];           // pitch 68 words: 2-way bank alias only
    int tid  = threadIdx.x;
    int wave = tid >> 6;
    int lane = tid & 63;
    int m16  = lane & 15;
    int quad = lane >> 4;
    int row  = blockIdx.x * 64 + wave * 16 + m16;
    int rowc = min(row, N - 1);

    // prefetch whole A row-fragment (16B x 2 per kt) — lands during staging
    const float4* a4 = (const float4*)(A + (size_t)rowc * K);
    float4 araw[2 * KT];
#pragma unroll
    for (int kt = 0; kt < KT; kt++) {
        araw[2 * kt]     = a4[kt * 8 + quad * 2];
        araw[2 * kt + 1] = a4[kt * 8 + quad * 2 + 1];
    }

    floatx4 acc[8];
#pragma unroll
    for (int c = 0; c < 8; c++) acc[c] = (floatx4){0.f, 0.f, 0.f, 0.f};

    int sn0 = tid >> 4;      // staging: n = i*16 + sn0
    int sq4 = tid & 15;      // word-group within chunk

    for (int ch = 0; ch < NCH; ch++) {
        // cooperative stage: 32KB chunk, 8 independent dwordx4 per thread
#pragma unroll
        for (int i = 0; i < 8; i++) {
            int n = i * 16 + sn0;
            *(uint4*)&Bs[n * 68 + sq4 * 4] =
                *(const uint4*)&Wp[(size_t)n * K + ch * 64 + sq4 * 4];
        }
        __syncthreads();

#pragma unroll
        for (int ktl = 0; ktl < 2; ktl++) {
            int ktg = ch * 2 + ktl;
            float4 f0 = araw[2 * ktg];
            float4 f1 = araw[2 * ktg + 1];
            uint ahw[4], alw[4];
            splitPair(f0.x, f0.y, ahw[0], alw[0]);
            splitPair(f0.z, f0.w, ahw[1], alw[1]);
            splitPair(f1.x, f1.y, ahw[2], alw[2]);
            splitPair(f1.z, f1.w, ahw[3], alw[3]);
            short8 a_hi = mk8(ahw[0], ahw[1], ahw[2], ahw[3]);
            short8 a_lo = mk8(alw[0], alw[1], alw[2], alw[3]);

#pragma unroll
            for (int c = 0; c < 8; c++) {
                const uint* bp = &Bs[(c * 16 + m16) * 68 + ktl * 32 + quad * 8];
                uint4 w0 = *(const uint4*)bp;
                uint4 w1 = *(const uint4*)(bp + 4);
                short8 b_hi = mk8(w0.x, w0.z, w1.x, w1.z);
                short8 b_lo = mk8(w0.y, w0.w, w1.y, w1.w);
                acc[c] = __builtin_amdgcn_mfma_f32_16x16x32_bf16(a_hi, b_hi, acc[c], 0, 0, 0);
                acc[c] = __builtin_amdgcn_mfma_f32_16x16x32_bf16(a_lo, b_hi, acc[c], 0, 0, 0);
                acc[c] = __builtin_amdgcn_mfma_f32_16x16x32_bf16(a_hi, b_lo, acc[c], 0, 0, 0);
            }
        }
        __syncthreads();
    }

    int rowbase = blockIdx.x * 64 + wave * 16 + quad * 4;
#pragma unroll
    for (int c = 0; c < 8; c++) {
#pragma unroll
        for (int r = 0; r < 4; r++) {
            int rr = rowbase + r;
            if (rr < N) out[(size_t)rr * HH + c * 16 + m16] = acc[c][r];
        }
    }
}

// ---------- CSR aggregation + fused epilogue ----------
// wave-per-node; half-wave edge split: lanes 0-31 even edges, 32-63 odd,
// float4/lane over 128 cols; shfl_xor(32) reduce; no barriers.
__global__ __launch_bounds__(256) void k_agg(const float* __restrict__ xw,
                                             const float* __restrict__ dinv,
                                             const int* __restrict__ rowptr,
                                             const int* __restrict__ csr_src,
                                             const float* __restrict__ b,
                                             const float* __restrict__ g,
                                             const float* __restrict__ beta,
                                             const float* __restrict__ m,
                                             const float* __restrict__ v,
                                             float* __restrict__ out,
                                             int N, int mode) {
    __shared__ int   sS[256];
    __shared__ float sD[256];
    int wave = threadIdx.x >> 6;
    int lane = threadIdx.x & 63;
    int n = blockIdx.x * 4 + wave;
    if (n >= N) return;
    int wbase = wave * 64;
    int h   = lane >> 5;      // edge parity
    int c32 = lane & 31;      // float4 column group

    int beg = rowptr[n];
    int end = rowptr[n + 1];
    float di = dinv[n];
    const float4* xw4 = (const float4*)xw;

    float4 acc = make_float4(0.f, 0.f, 0.f, 0.f);
    if (h == 0) {
        float4 self = xw4[(size_t)n * 32 + c32];
        acc.x = di * self.x; acc.y = di * self.y;
        acc.z = di * self.z; acc.w = di * self.w;
    }

    for (int base = beg; base < end; base += 64) {
        int cnt = min(64, end - base);
        if (lane < cnt) {
            int s = csr_src[base + lane];
            sS[wbase + lane] = s;
            sD[wbase + lane] = dinv[s];
        }
        // same-wave LDS write->read: compiler inserts lgkmcnt wait
#pragma unroll 4
        for (int j = h; j < cnt; j += 2) {
            int sj   = sS[wbase + j];
            float dj = sD[wbase + j];
            float4 r = xw4[(size_t)sj * 32 + c32];
            acc.x = fmaf(dj, r.x, acc.x);
            acc.y = fmaf(dj, r.y, acc.y);
            acc.z = fmaf(dj, r.z, acc.z);
            acc.w = fmaf(dj, r.w, acc.w);
        }
    }

    // combine the two half-wave partial sums
    acc.x += __shfl_xor(acc.x, 32, 64);
    acc.y += __shfl_xor(acc.y, 32, 64);
    acc.z += __shfl_xor(acc.z, 32, 64);
    acc.w += __shfl_xor(acc.w, 32, 64);

    if (h == 0) {
        float4 bb = ((const float4*)b)[c32];
        float4 val;
        val.x = di * acc.x + bb.x;
        val.y = di * acc.y + bb.y;
        val.z = di * acc.z + bb.z;
        val.w = di * acc.w + bb.w;
        if (mode) {
            float4 mm = ((const float4*)m)[c32];
            float4 vv = ((const float4*)v)[c32];
            float4 gg = ((const float4*)g)[c32];
            float4 be = ((const float4*)beta)[c32];
            val.x = fmaxf((val.x - mm.x) * rsqrtf(vv.x + BN_EPS) * gg.x + be.x, 0.f);
            val.y = fmaxf((val.y - mm.y) * rsqrtf(vv.y + BN_EPS) * gg.y + be.y, 0.f);
            val.z = fmaxf((val.z - mm.z) * rsqrtf(vv.z + BN_EPS) * gg.z + be.z, 0.f);
            val.w = fmaxf((val.w - mm.w) * rsqrtf(vv.w + BN_EPS) * gg.w + be.w, 0.f);
        }
        ((float4*)out)[(size_t)n * 32 + c32] = val;
    }
}

// ---------- pool ----------
__global__ __launch_bounds__(128) void k_pool(const float* __restrict__ h,
                                              const int* __restrict__ batch,
                                              float* __restrict__ sums,
                                              float* __restrict__ cnts, int N) {
    int col = threadIdx.x;
    int n0 = blockIdx.x * 128;
    int n1 = min(n0 + 128, N);
    float acc = 0.0f;
    float cnt = 0.0f;
    int curg = batch[n0];
    for (int n = n0; n < n1; n++) {
        int gg = batch[n];
        if (gg != curg) {
            atomAddF(&sums[(size_t)curg * HH + col], acc);
            if (col == 0) atomAddF(&cnts[curg], cnt);
            acc = 0.0f; cnt = 0.0f; curg = gg;
        }
        acc += h[(size_t)n * HH + col];
        cnt += 1.0f;
    }
    atomAddF(&sums[(size_t)curg * HH + col], acc);
    if (col == 0) atomAddF(&cnts[curg], cnt);
}

// ---------- classifier head ----------
__global__ __launch_bounds__(64) void k_cls(const float* __restrict__ sums,
                                            const float* __restrict__ cnts,
                                            const float* __restrict__ Wc1,
                                            const float* __restrict__ bc1,
                                            const float* __restrict__ Wc2,
                                            const float* __restrict__ bc2,
                                            float* __restrict__ out, int Hc, int C) {
    int gI = blockIdx.x;
    int tid = threadIdx.x;
    __shared__ float pooled[HH];
    __shared__ float z[64];
    float cnt = fmaxf(cnts[gI], 1.0f);
    for (int c = tid; c < HH; c += 64) pooled[c] = sums[(size_t)gI * HH + c] / cnt;
    __syncthreads();
    if (tid < Hc) {
        float a = bc1[tid];
        for (int k = 0; k < HH; k++) a += pooled[k] * Wc1[k * Hc + tid];
        z[tid] = fmaxf(a, 0.0f);
    }
    __syncthreads();
    if (tid < C) {
        float a = bc2[tid];
        for (int k = 0; k < Hc; k++) a += z[k] * Wc2[k * C + tid];
        out[(size_t)gI * C + tid] = a;
    }
}

extern "C" void kernel_launch(void* const* d_in, const int* in_sizes, int n_in,
                              void* d_out, int out_size, void* d_ws, size_t ws_size,
                              hipStream_t stream) {
    const float* x     = (const float*)d_in[0];
    const int*   ei    = (const int*)d_in[1];
    const int*   batch = (const int*)d_in[2];
    const float* W1    = (const float*)d_in[3];
    const float* b1    = (const float*)d_in[4];
    const float* W2    = (const float*)d_in[5];
    const float* b2    = (const float*)d_in[6];
    const float* W3    = (const float*)d_in[7];
    const float* b3    = (const float*)d_in[8];
    const float* bn1_g = (const float*)d_in[9];
    const float* bn1_b = (const float*)d_in[10];
    const float* bn1_m = (const float*)d_in[11];
    const float* bn1_v = (const float*)d_in[12];
    const float* bn2_g = (const float*)d_in[13];
    const float* bn2_b = (const float*)d_in[14];
    const float* bn2_m = (const float*)d_in[15];
    const float* bn2_v = (const float*)d_in[16];
    const float* Wc1   = (const float*)d_in[17];
    const float* bc1   = (const float*)d_in[18];
    const float* Wc2   = (const float*)d_in[19];
    const float* bc2   = (const float*)d_in[20];
    float* out = (float*)d_out;

    const int N  = in_sizes[2];
    const int E  = in_sizes[1] / 2;
    const int K0 = in_sizes[0] / N;      // 256
    const int Hc = in_sizes[18];         // 64
    const int C  = in_sizes[20];         // 16
    const int G  = out_size / C;         // 64

    const int* srcv = ei;
    const int* dstv = ei + E;

    // workspace layout
    float* ws = (float*)d_ws;
    size_t NH = (size_t)N * HH;
    size_t Na = (((size_t)N + 255) / 256) * 256;
    float* bufA    = ws;
    float* bufB    = bufA + NH;
    float* dinv    = bufB + NH;
    float* degf    = dinv + Na;
    int*   rowptr  = (int*)(degf + Na);
    int*   cursor  = rowptr + Na + 256;
    int*   csr_src = cursor + Na;
    int*   partials= csr_src + (((size_t)E + 255) / 256) * 256;
    float* sums    = (float*)(partials + 256);
    float* cnts    = sums + (size_t)G * HH;
    uint*  Wp1     = (uint*)(cnts + 256);
    uint*  Wp2     = Wp1 + (size_t)K0 * HH;
    uint*  Wp3     = Wp2 + (size_t)HH * HH;

    const int T = 256;
    int gN   = (N + T - 1) / T;
    int gE   = (E + T - 1) / T;
    int nb   = gN;
    int gGemm = (N + 63) / 64;
    int gAgg  = (N + 3) / 4;
    int gPool = (N + 127) / 128;

    // degree -> dinv, CSR build
    hipMemsetAsync(degf, 0, N * sizeof(float), stream);
    k_deg<<<gE, T, 0, stream>>>(dstv, degf, E);
    k_dinv<<<gN, T, 0, stream>>>(degf, dinv, N);
    k_scanA<<<nb, 256, 0, stream>>>(degf, partials, N);
    k_scanB<<<1, 256, 0, stream>>>(partials, nb);
    k_scanC<<<nb, 256, 0, stream>>>(degf, partials, rowptr, cursor, N);
    k_fill<<<gE, T, 0, stream>>>(srcv, dstv, cursor, csr_src, E);

    // weight splits
    k_wsplit<<<(128 * (K0 / 2) + 255) / 256, 256, 0, stream>>>(W1, Wp1, K0);
    k_wsplit<<<(128 * (HH / 2) + 255) / 256, 256, 0, stream>>>(W2, Wp2, HH);
    k_wsplit<<<(128 * (HH / 2) + 255) / 256, 256, 0, stream>>>(W3, Wp3, HH);

    // layer 1
    if (K0 == 256)
        k_gemm_mfma<8><<<gGemm, 256, 0, stream>>>(x, Wp1, bufA, N);
    else
        k_gemm_mfma<4><<<gGemm, 256, 0, stream>>>(x, Wp1, bufA, N);
    k_agg<<<gAgg, 256, 0, stream>>>(bufA, dinv, rowptr, csr_src, b1,
                                    bn1_g, bn1_b, bn1_m, bn1_v, bufB, N, 1);
    // layer 2
    k_gemm_mfma<4><<<gGemm, 256, 0, stream>>>(bufB, Wp2, bufA, N);
    k_agg<<<gAgg, 256, 0, stream>>>(bufA, dinv, rowptr, csr_src, b2,
                                    bn2_g, bn2_b, bn2_m, bn2_v, bufB, N, 1);
    // layer 3
    k_gemm_mfma<4><<<gGemm, 256, 0, stream>>>(bufB, Wp3, bufA, N);
    k_agg<<<gAgg, 256, 0, stream>>>(bufA, dinv, rowptr, csr_src, b3,
                                    nullptr, nullptr, nullptr, nullptr, bufB, N, 0);

    // pool + classifier
    hipMemsetAsync(sums, 0, ((size_t)G * HH + G) * sizeof(float), stream);
    k_pool<<<gPool, 128, 0, stream>>>(bufB, batch, sums, cnts, N);
    k_cls<<<G, 64, 0, stream>>>(sums, cnts, Wc1, bc1, Wc2, bc2, out, Hc, C);
}

// Round 6
// 429.144 us; speedup vs baseline: 4.3987x; 1.1493x over previous
//
#include <hip/hip_runtime.h>

#define HH 128
#define BN_EPS 1e-5f

typedef __attribute__((ext_vector_type(8))) short short8;
typedef __attribute__((ext_vector_type(4))) float floatx4;

__device__ inline void atomAddF(float* p, float v) { unsafeAtomicAdd(p, v); }

__device__ inline short8 mk8(uint a, uint b, uint c, uint d) {
    union { uint u[4]; short8 s; } t;
    t.u[0] = a; t.u[1] = b; t.u[2] = c; t.u[3] = d;
    return t.s;
}

// fp32 -> bf16 round-to-nearest-even (bits)
__device__ inline ushort f2bf(float f) {
    uint u = __float_as_uint(f);
    u = u + 0x7FFFu + ((u >> 16) & 1u);
    return (ushort)(u >> 16);
}

// split one float pair into hi-word / lo-word (bf16x2 each)
__device__ inline void splitPair(float f0, float f1, uint& hw, uint& lw) {
    uint u0 = __float_as_uint(f0), u1 = __float_as_uint(f1);
    hw = __builtin_amdgcn_perm(u1, u0, 0x07060302);
    float r0 = f0 - __uint_as_float(u0 & 0xFFFF0000u);
    float r1 = f1 - __uint_as_float(u1 & 0xFFFF0000u);
    lw = __builtin_amdgcn_perm(__float_as_uint(r1), __float_as_uint(r0), 0x07060302);
}

// ---------- degree / norm ----------
__global__ void k_deg(const int* __restrict__ dst, float* __restrict__ degf, int E) {
    int i = blockIdx.x * blockDim.x + threadIdx.x;
    if (i < E) atomAddF(&degf[dst[i]], 1.0f);
}

__global__ void k_dinv(const float* __restrict__ degf, float* __restrict__ dinv, int n) {
    int i = blockIdx.x * blockDim.x + threadIdx.x;
    if (i < n) dinv[i] = rsqrtf(degf[i] + 1.0f);   // +1 self-loop
}

// ---------- CSR build ----------
__global__ __launch_bounds__(256) void k_scanA(const float* __restrict__ degf,
                                               int* __restrict__ partials, int N) {
    __shared__ int s[256];
    int i = blockIdx.x * 256 + threadIdx.x;
    int d = (i < N) ? (int)degf[i] : 0;
    s[threadIdx.x] = d;
    __syncthreads();
    for (int off = 128; off > 0; off >>= 1) {
        if (threadIdx.x < off) s[threadIdx.x] += s[threadIdx.x + off];
        __syncthreads();
    }
    if (threadIdx.x == 0) partials[blockIdx.x] = s[0];
}

__global__ __launch_bounds__(256) void k_scanB(int* __restrict__ partials, int nb) {
    __shared__ int s[256];
    int tid = threadIdx.x;
    int v = (tid < nb) ? partials[tid] : 0;
    s[tid] = v;
    __syncthreads();
    for (int off = 1; off < 256; off <<= 1) {
        int t = (tid >= off) ? s[tid - off] : 0;
        __syncthreads();
        s[tid] += t;
        __syncthreads();
    }
    partials[tid] = s[tid] - v;   // exclusive
}

__global__ __launch_bounds__(256) void k_scanC(const float* __restrict__ degf,
                                               const int* __restrict__ partials,
                                               int* __restrict__ rowptr,
                                               int* __restrict__ cursor, int N) {
    __shared__ int s[256];
    int tid = threadIdx.x;
    int i = blockIdx.x * 256 + tid;
    int d = (i < N) ? (int)degf[i] : 0;
    s[tid] = d;
    __syncthreads();
    for (int off = 1; off < 256; off <<= 1) {
        int t = (tid >= off) ? s[tid - off] : 0;
        __syncthreads();
        s[tid] += t;
        __syncthreads();
    }
    int incl = s[tid];
    int base = partials[blockIdx.x];
    if (i < N) {
        rowptr[i] = base + incl - d;
        cursor[i] = base + incl - d;
        if (i == N - 1) rowptr[N] = base + incl;
    }
}

__global__ void k_fill(const int* __restrict__ src, const int* __restrict__ dst,
                       int* __restrict__ cursor, int* __restrict__ csr_src, int E) {
    int e = blockIdx.x * blockDim.x + threadIdx.x;
    if (e < E) {
        int pos = atomicAdd(&cursor[dst[e]], 1);
        csr_src[pos] = src[e];
    }
}

// ---------- W split: W[K,128] -> packed transposed Wp[128][K] words ----------
__global__ void k_wsplit(const float* __restrict__ W, uint* __restrict__ Wp, int K) {
    int t = blockIdx.x * 256 + threadIdx.x;
    int half = K >> 1;
    if (t >= 128 * half) return;
    int n = t / half;
    int p = t - n * half;
    uint hw, lw;
    splitPair(W[(2 * p) * HH + n], W[(2 * p + 1) * HH + n], hw, lw);
    Wp[n * K + 2 * p]     = hw;
    Wp[n * K + 2 * p + 1] = lw;
}

// ---------- MFMA GEMM: A[N,K] fp32 @ W[K,128] -> out[N,128] bf16 ----------
// B staged in LDS per 64-word K-chunk; inner = ds_read_b128 + MFMA.
// A row-fragment prefetched to VGPRs. Epilogue stores bf16 (RTN).
template<int KT>   // K = KT*32
__global__ __launch_bounds__(256) void k_gemm_mfma(const float* __restrict__ A,
                                                   const uint* __restrict__ Wp,
                                                   ushort* __restrict__ out,
                                                   int N) {
    const int K = KT * 32;
    const int NCH = KT / 2;                 // 64-word chunks
    __shared__ uint Bs[128 * 68];           // 34.8 KB, pitch 68: 2-way alias only
    int tid  = threadIdx.x;
    int wave = tid >> 6;
    int lane = tid & 63;
    int m16  = lane & 15;
    int quad = lane >> 4;
    int row  = blockIdx.x * 64 + wave * 16 + m16;
    int rowc = min(row, N - 1);

    const float4* a4 = (const float4*)(A + (size_t)rowc * K);
    float4 araw[2 * KT];
#pragma unroll
    for (int kt = 0; kt < KT; kt++) {
        araw[2 * kt]     = a4[kt * 8 + quad * 2];
        araw[2 * kt + 1] = a4[kt * 8 + quad * 2 + 1];
    }

    floatx4 acc[8];
#pragma unroll
    for (int c = 0; c < 8; c++) acc[c] = (floatx4){0.f, 0.f, 0.f, 0.f};

    int sn0 = tid >> 4;
    int sq4 = tid & 15;

    for (int ch = 0; ch < NCH; ch++) {
#pragma unroll
        for (int i = 0; i < 8; i++) {
            int n = i * 16 + sn0;
            *(uint4*)&Bs[n * 68 + sq4 * 4] =
                *(const uint4*)&Wp[(size_t)n * K + ch * 64 + sq4 * 4];
        }
        __syncthreads();

#pragma unroll
        for (int ktl = 0; ktl < 2; ktl++) {
            int ktg = ch * 2 + ktl;
            float4 f0 = araw[2 * ktg];
            float4 f1 = araw[2 * ktg + 1];
            uint ahw[4], alw[4];
            splitPair(f0.x, f0.y, ahw[0], alw[0]);
            splitPair(f0.z, f0.w, ahw[1], alw[1]);
            splitPair(f1.x, f1.y, ahw[2], alw[2]);
            splitPair(f1.z, f1.w, ahw[3], alw[3]);
            short8 a_hi = mk8(ahw[0], ahw[1], ahw[2], ahw[3]);
            short8 a_lo = mk8(alw[0], alw[1], alw[2], alw[3]);

#pragma unroll
            for (int c = 0; c < 8; c++) {
                const uint* bp = &Bs[(c * 16 + m16) * 68 + ktl * 32 + quad * 8];
                uint4 w0 = *(const uint4*)bp;
                uint4 w1 = *(const uint4*)(bp + 4);
                short8 b_hi = mk8(w0.x, w0.z, w1.x, w1.z);
                short8 b_lo = mk8(w0.y, w0.w, w1.y, w1.w);
                acc[c] = __builtin_amdgcn_mfma_f32_16x16x32_bf16(a_hi, b_hi, acc[c], 0, 0, 0);
                acc[c] = __builtin_amdgcn_mfma_f32_16x16x32_bf16(a_lo, b_hi, acc[c], 0, 0, 0);
                acc[c] = __builtin_amdgcn_mfma_f32_16x16x32_bf16(a_hi, b_lo, acc[c], 0, 0, 0);
            }
        }
        __syncthreads();
    }

    int rowbase = blockIdx.x * 64 + wave * 16 + quad * 4;
#pragma unroll
    for (int c = 0; c < 8; c++) {
#pragma unroll
        for (int r = 0; r < 4; r++) {
            int rr = rowbase + r;
            if (rr < N) out[(size_t)rr * HH + c * 16 + m16] = f2bf(acc[c][r]);
        }
    }
}

// ---------- CSR aggregation (bf16 gather) + fused epilogue ----------
// wave-per-node; lanes 0-31 even edges, 32-63 odd; 4 cols (8B bf16) per lane.
__global__ __launch_bounds__(256) void k_agg(const ushort* __restrict__ xwb,
                                             const float* __restrict__ dinv,
                                             const int* __restrict__ rowptr,
                                             const int* __restrict__ csr_src,
                                             const float* __restrict__ b,
                                             const float* __restrict__ g,
                                             const float* __restrict__ beta,
                                             const float* __restrict__ m,
                                             const float* __restrict__ v,
                                             float* __restrict__ out,
                                             int N, int mode) {
    __shared__ int   sS[256];
    __shared__ float sD[256];
    int wave = threadIdx.x >> 6;
    int lane = threadIdx.x & 63;
    int n = blockIdx.x * 4 + wave;
    if (n >= N) return;
    int wbase = wave * 64;
    int h   = lane >> 5;      // edge parity
    int c32 = lane & 31;      // 4-col group

    int beg = rowptr[n];
    int end = rowptr[n + 1];
    float di = dinv[n];
    const uint2* xw2 = (const uint2*)xwb;   // row = 32 x uint2 (4 bf16 each)

    float4 acc = make_float4(0.f, 0.f, 0.f, 0.f);
    if (h == 0) {
        uint2 w = xw2[(size_t)n * 32 + c32];
        acc.x = di * __uint_as_float(w.x << 16);
        acc.y = di * __uint_as_float(w.x & 0xFFFF0000u);
        acc.z = di * __uint_as_float(w.y << 16);
        acc.w = di * __uint_as_float(w.y & 0xFFFF0000u);
    }

    for (int base = beg; base < end; base += 64) {
        int cnt = min(64, end - base);
        if (lane < cnt) {
            int s = csr_src[base + lane];
            sS[wbase + lane] = s;
            sD[wbase + lane] = dinv[s];
        }
#pragma unroll 4
        for (int j = h; j < cnt; j += 2) {
            int sj   = sS[wbase + j];
            float dj = sD[wbase + j];
            uint2 w = xw2[(size_t)sj * 32 + c32];
            acc.x = fmaf(dj, __uint_as_float(w.x << 16), acc.x);
            acc.y = fmaf(dj, __uint_as_float(w.x & 0xFFFF0000u), acc.y);
            acc.z = fmaf(dj, __uint_as_float(w.y << 16), acc.z);
            acc.w = fmaf(dj, __uint_as_float(w.y & 0xFFFF0000u), acc.w);
        }
    }

    acc.x += __shfl_xor(acc.x, 32, 64);
    acc.y += __shfl_xor(acc.y, 32, 64);
    acc.z += __shfl_xor(acc.z, 32, 64);
    acc.w += __shfl_xor(acc.w, 32, 64);

    if (h == 0) {
        float4 bb = ((const float4*)b)[c32];
        float4 val;
        val.x = di * acc.x + bb.x;
        val.y = di * acc.y + bb.y;
        val.z = di * acc.z + bb.z;
        val.w = di * acc.w + bb.w;
        if (mode) {
            float4 mm = ((const float4*)m)[c32];
            float4 vv = ((const float4*)v)[c32];
            float4 gg = ((const float4*)g)[c32];
            float4 be = ((const float4*)beta)[c32];
            val.x = fmaxf((val.x - mm.x) * rsqrtf(vv.x + BN_EPS) * gg.x + be.x, 0.f);
            val.y = fmaxf((val.y - mm.y) * rsqrtf(vv.y + BN_EPS) * gg.y + be.y, 0.f);
            val.z = fmaxf((val.z - mm.z) * rsqrtf(vv.z + BN_EPS) * gg.z + be.z, 0.f);
            val.w = fmaxf((val.w - mm.w) * rsqrtf(vv.w + BN_EPS) * gg.w + be.w, 0.f);
        }
        ((float4*)out)[(size_t)n * 32 + c32] = val;
    }
}

// ---------- pool ----------
__global__ __launch_bounds__(128) void k_pool(const float* __restrict__ h,
                                              const int* __restrict__ batch,
                                              float* __restrict__ sums,
                                              float* __restrict__ cnts, int N) {
    int col = threadIdx.x;
    int n0 = blockIdx.x * 128;
    int n1 = min(n0 + 128, N);
    float acc = 0.0f;
    float cnt = 0.0f;
    int curg = batch[n0];
    for (int n = n0; n < n1; n++) {
        int gg = batch[n];
        if (gg != curg) {
            atomAddF(&sums[(size_t)curg * HH + col], acc);
            if (col == 0) atomAddF(&cnts[curg], cnt);
            acc = 0.0f; cnt = 0.0f; curg = gg;
        }
        acc += h[(size_t)n * HH + col];
        cnt += 1.0f;
    }
    atomAddF(&sums[(size_t)curg * HH + col], acc);
    if (col == 0) atomAddF(&cnts[curg], cnt);
}

// ---------- classifier head ----------
__global__ __launch_bounds__(64) void k_cls(const float* __restrict__ sums,
                                            const float* __restrict__ cnts,
                                            const float* __restrict__ Wc1,
                                            const float* __restrict__ bc1,
                                            const float* __restrict__ Wc2,
                                            const float* __restrict__ bc2,
                                            float* __restrict__ out, int Hc, int C) {
    int gI = blockIdx.x;
    int tid = threadIdx.x;
    __shared__ float pooled[HH];
    __shared__ float z[64];
    float cnt = fmaxf(cnts[gI], 1.0f);
    for (int c = tid; c < HH; c += 64) pooled[c] = sums[(size_t)gI * HH + c] / cnt;
    __syncthreads();
    if (tid < Hc) {
        float a = bc1[tid];
        for (int k = 0; k < HH; k++) a += pooled[k] * Wc1[k * Hc + tid];
        z[tid] = fmaxf(a, 0.0f);
    }
    __syncthreads();
    if (tid < C) {
        float a = bc2[tid];
        for (int k = 0; k < Hc; k++) a += z[k] * Wc2[k * C + tid];
        out[(size_t)gI * C + tid] = a;
    }
}

extern "C" void kernel_launch(void* const* d_in, const int* in_sizes, int n_in,
                              void* d_out, int out_size, void* d_ws, size_t ws_size,
                              hipStream_t stream) {
    const float* x     = (const float*)d_in[0];
    const int*   ei    = (const int*)d_in[1];
    const int*   batch = (const int*)d_in[2];
    const float* W1    = (const float*)d_in[3];
    const float* b1    = (const float*)d_in[4];
    const float* W2    = (const float*)d_in[5];
    const float* b2    = (const float*)d_in[6];
    const float* W3    = (const float*)d_in[7];
    const float* b3    = (const float*)d_in[8];
    const float* bn1_g = (const float*)d_in[9];
    const float* bn1_b = (const float*)d_in[10];
    const float* bn1_m = (const float*)d_in[11];
    const float* bn1_v = (const float*)d_in[12];
    const float* bn2_g = (const float*)d_in[13];
    const float* bn2_b = (const float*)d_in[14];
    const float* bn2_m = (const float*)d_in[15];
    const float* bn2_v = (const float*)d_in[16];
    const float* Wc1   = (const float*)d_in[17];
    const float* bc1   = (const float*)d_in[18];
    const float* Wc2   = (const float*)d_in[19];
    const float* bc2   = (const float*)d_in[20];
    float* out = (float*)d_out;

    const int N  = in_sizes[2];
    const int E  = in_sizes[1] / 2;
    const int K0 = in_sizes[0] / N;      // 256
    const int Hc = in_sizes[18];         // 64
    const int C  = in_sizes[20];         // 16
    const int G  = out_size / C;         // 64

    const int* srcv = ei;
    const int* dstv = ei + E;

    // workspace layout (bufA reinterpreted as bf16 but keeps fp32-sized slot)
    float* ws = (float*)d_ws;
    size_t NH = (size_t)N * HH;
    size_t Na = (((size_t)N + 255) / 256) * 256;
    ushort* bufA  = (ushort*)ws;         // N*128 bf16 (uses half the slot)
    float* bufB    = ws + NH;
    float* dinv    = bufB + NH;
    float* degf    = dinv + Na;
    int*   rowptr  = (int*)(degf + Na);
    int*   cursor  = rowptr + Na + 256;
    int*   csr_src = cursor + Na;
    int*   partials= csr_src + (((size_t)E + 255) / 256) * 256;
    float* sums    = (float*)(partials + 256);
    float* cnts    = sums + (size_t)G * HH;
    uint*  Wp1     = (uint*)(cnts + 256);
    uint*  Wp2     = Wp1 + (size_t)K0 * HH;
    uint*  Wp3     = Wp2 + (size_t)HH * HH;

    const int T = 256;
    int gN   = (N + T - 1) / T;
    int gE   = (E + T - 1) / T;
    int nb   = gN;
    int gGemm = (N + 63) / 64;
    int gAgg  = (N + 3) / 4;
    int gPool = (N + 127) / 128;

    // degree -> dinv, CSR build
    hipMemsetAsync(degf, 0, N * sizeof(float), stream);
    k_deg<<<gE, T, 0, stream>>>(dstv, degf, E);
    k_dinv<<<gN, T, 0, stream>>>(degf, dinv, N);
    k_scanA<<<nb, 256, 0, stream>>>(degf, partials, N);
    k_scanB<<<1, 256, 0, stream>>>(partials, nb);
    k_scanC<<<nb, 256, 0, stream>>>(degf, partials, rowptr, cursor, N);
    k_fill<<<gE, T, 0, stream>>>(srcv, dstv, cursor, csr_src, E);

    // weight splits
    k_wsplit<<<(128 * (K0 / 2) + 255) / 256, 256, 0, stream>>>(W1, Wp1, K0);
    k_wsplit<<<(128 * (HH / 2) + 255) / 256, 256, 0, stream>>>(W2, Wp2, HH);
    k_wsplit<<<(128 * (HH / 2) + 255) / 256, 256, 0, stream>>>(W3, Wp3, HH);

    // layer 1
    if (K0 == 256)
        k_gemm_mfma<8><<<gGemm, 256, 0, stream>>>(x, Wp1, bufA, N);
    else
        k_gemm_mfma<4><<<gGemm, 256, 0, stream>>>(x, Wp1, bufA, N);
    k_agg<<<gAgg, 256, 0, stream>>>(bufA, dinv, rowptr, csr_src, b1,
                                    bn1_g, bn1_b, bn1_m, bn1_v, bufB, N, 1);
    // layer 2
    k_gemm_mfma<4><<<gGemm, 256, 0, stream>>>(bufB, Wp2, bufA, N);
    k_agg<<<gAgg, 256, 0, stream>>>(bufA, dinv, rowptr, csr_src, b2,
                                    bn2_g, bn2_b, bn2_m, bn2_v, bufB, N, 1);
    // layer 3
    k_gemm_mfma<4><<<gGemm, 256, 0, stream>>>(bufB, Wp3, bufA, N);
    k_agg<<<gAgg, 256, 0, stream>>>(bufA, dinv, rowptr, csr_src, b3,
                                    nullptr, nullptr, nullptr, nullptr, bufB, N, 0);

    // pool + classifier
    hipMemsetAsync(sums, 0, ((size_t)G * HH + G) * sizeof(float), stream);
    k_pool<<<gPool, 128, 0, stream>>>(bufB, batch, sums, cnts, N);
    k_cls<<<G, 64, 0, stream>>>(sums, cnts, Wc1, bc1, Wc2, bc2, out, Hc, C);
}

// Round 7
// 387.050 us; speedup vs baseline: 4.8771x; 1.1088x over previous
//
#include <hip/hip_runtime.h>

#define HH 128
#define BN_EPS 1e-5f

typedef __attribute__((ext_vector_type(8))) short short8;
typedef __attribute__((ext_vector_type(4))) float floatx4;

__device__ inline void atomAddF(float* p, float v) { unsafeAtomicAdd(p, v); }

__device__ inline short8 mk8(uint a, uint b, uint c, uint d) {
    union { uint u[4]; short8 s; } t;
    t.u[0] = a; t.u[1] = b; t.u[2] = c; t.u[3] = d;
    return t.s;
}

__device__ inline ushort f2bf(float f) {
    uint u = __float_as_uint(f);
    u = u + 0x7FFFu + ((u >> 16) & 1u);
    return (ushort)(u >> 16);
}

__device__ inline float bfLo(uint u) { return __uint_as_float(u << 16); }
__device__ inline float bfHi(uint u) { return __uint_as_float(u & 0xFFFF0000u); }

__device__ inline void splitPair(float f0, float f1, uint& hw, uint& lw) {
    uint u0 = __float_as_uint(f0), u1 = __float_as_uint(f1);
    hw = __builtin_amdgcn_perm(u1, u0, 0x07060302);
    float r0 = f0 - __uint_as_float(u0 & 0xFFFF0000u);
    float r1 = f1 - __uint_as_float(u1 & 0xFFFF0000u);
    lw = __builtin_amdgcn_perm(__float_as_uint(r1), __float_as_uint(r0), 0x07060302);
}

// ================= CSR build via 2-level bucket sort (NO global atomics) ====
// digit1 = dst>>8 (256 buckets), digit2 = dst&255. Order within a node's list
// is arbitrary (sum is order-independent).

// pass A1: per-block histogram of high byte
__global__ __launch_bounds__(256) void k_ahist(const int* __restrict__ dst,
                                               int* __restrict__ gH, int E, int tile) {
    __shared__ int hist[256];
    int b = blockIdx.x, tid = threadIdx.x;
    hist[tid] = 0;
    __syncthreads();
    int s0 = b * tile, s1 = min(s0 + tile, E);
    for (int i = s0 + tid; i < s1; i += 256)
        atomicAdd(&hist[((unsigned)dst[i]) >> 8], 1);
    __syncthreads();
    gH[tid * 256 + b] = hist[tid];    // h-major layout
}

// pass A2: per-bucket exclusive scan over blocks
__global__ __launch_bounds__(256) void k_scan1(const int* __restrict__ gH,
                                               int* __restrict__ gC,
                                               int* __restrict__ totals) {
    __shared__ int s[256];
    int h = blockIdx.x, b = threadIdx.x;
    int v = gH[h * 256 + b];
    s[b] = v;
    __syncthreads();
    for (int off = 1; off < 256; off <<= 1) {
        int t = (b >= off) ? s[b - off] : 0;
        __syncthreads();
        s[b] += t;
        __syncthreads();
    }
    gC[h * 256 + b] = s[b] - v;
    if (b == 255) totals[h] = s[255];
}

// pass A3: exclusive scan of bucket totals -> base[257]
__global__ __launch_bounds__(256) void k_scan2(const int* __restrict__ totals,
                                               int* __restrict__ base) {
    __shared__ int s[256];
    int tid = threadIdx.x;
    int v = totals[tid];
    s[tid] = v;
    __syncthreads();
    for (int off = 1; off < 256; off <<= 1) {
        int t = (tid >= off) ? s[tid - off] : 0;
        __syncthreads();
        s[tid] += t;
        __syncthreads();
    }
    base[tid] = s[tid] - v;
    if (tid == 255) base[256] = s[255];
}

// pass A4: scatter edges into buckets (LDS cursors, block-exclusive runs)
__global__ __launch_bounds__(256) void k_asc(const int* __restrict__ src,
                                             const int* __restrict__ dst,
                                             const int* __restrict__ gC,
                                             const int* __restrict__ base,
                                             uint2* __restrict__ bucketed,
                                             int E, int tile) {
    __shared__ int cur[256];
    int b = blockIdx.x, tid = threadIdx.x;
    cur[tid] = gC[tid * 256 + b] + base[tid];
    __syncthreads();
    int s0 = b * tile, s1 = min(s0 + tile, E);
    for (int i = s0 + tid; i < s1; i += 256) {
        int d = dst[i];
        int pos = atomicAdd(&cur[((unsigned)d) >> 8], 1);
        bucketed[pos] = make_uint2((uint)src[i], (uint)d);
    }
}

// pass B: per-bucket low-byte histogram == degree; fused dinv
__global__ __launch_bounds__(256) void k_bdeg(const uint2* __restrict__ bucketed,
                                              const int* __restrict__ base,
                                              int* __restrict__ degInt,
                                              float* __restrict__ dinv, int N) {
    __shared__ int hist[256];
    int h = blockIdx.x, tid = threadIdx.x;
    hist[tid] = 0;
    __syncthreads();
    int s0 = base[h], s1 = base[h + 1];
    for (int i = s0 + tid; i < s1; i += 256)
        atomicAdd(&hist[bucketed[i].y & 255u], 1);
    __syncthreads();
    int n = h * 256 + tid;
    if (n < N) {
        int d = hist[tid];
        degInt[n] = d;
        dinv[n] = rsqrtf((float)d + 1.0f);   // +1 self-loop
    }
}

// ---------- rowptr scan over degInt ----------
__global__ __launch_bounds__(256) void k_scanA(const int* __restrict__ degInt,
                                               int* __restrict__ partials, int N) {
    __shared__ int s[256];
    int i = blockIdx.x * 256 + threadIdx.x;
    int d = (i < N) ? degInt[i] : 0;
    s[threadIdx.x] = d;
    __syncthreads();
    for (int off = 128; off > 0; off >>= 1) {
        if (threadIdx.x < off) s[threadIdx.x] += s[threadIdx.x + off];
        __syncthreads();
    }
    if (threadIdx.x == 0) partials[blockIdx.x] = s[0];
}

__global__ __launch_bounds__(256) void k_scanB(int* __restrict__ partials, int nb) {
    __shared__ int s[256];
    int tid = threadIdx.x;
    int v = (tid < nb) ? partials[tid] : 0;
    s[tid] = v;
    __syncthreads();
    for (int off = 1; off < 256; off <<= 1) {
        int t = (tid >= off) ? s[tid - off] : 0;
        __syncthreads();
        s[tid] += t;
        __syncthreads();
    }
    partials[tid] = s[tid] - v;
}

__global__ __launch_bounds__(256) void k_scanC(const int* __restrict__ degInt,
                                               const int* __restrict__ partials,
                                               int* __restrict__ rowptr, int N) {
    __shared__ int s[256];
    int tid = threadIdx.x;
    int i = blockIdx.x * 256 + tid;
    int d = (i < N) ? degInt[i] : 0;
    s[tid] = d;
    __syncthreads();
    for (int off = 1; off < 256; off <<= 1) {
        int t = (tid >= off) ? s[tid - off] : 0;
        __syncthreads();
        s[tid] += t;
        __syncthreads();
    }
    int incl = s[tid];
    int b = partials[blockIdx.x];
    if (i < N) {
        rowptr[i] = b + incl - d;
        if (i == N - 1) rowptr[N] = b + incl;
    }
}

// pass C: per-bucket scatter of src into CSR (LDS cursors from rowptr)
__global__ __launch_bounds__(256) void k_csc(const uint2* __restrict__ bucketed,
                                             const int* __restrict__ base,
                                             const int* __restrict__ rowptr,
                                             int* __restrict__ csr_src, int N) {
    __shared__ int cur[256];
    int h = blockIdx.x, tid = threadIdx.x;
    int n = h * 256 + tid;
    cur[tid] = (n < N) ? rowptr[n] : 0;
    __syncthreads();
    int s0 = base[h], s1 = base[h + 1];
    for (int i = s0 + tid; i < s1; i += 256) {
        uint2 e = bucketed[i];
        int pos = atomicAdd(&cur[e.y & 255u], 1);
        csr_src[pos] = (int)e.x;
    }
}

// ---------- W split: W[K,128] -> packed transposed Wp[128][K] words ----------
__global__ void k_wsplit(const float* __restrict__ W, uint* __restrict__ Wp, int K) {
    int t = blockIdx.x * 256 + threadIdx.x;
    int half = K >> 1;
    if (t >= 128 * half) return;
    int n = t / half;
    int p = t - n * half;
    uint hw, lw;
    splitPair(W[(2 * p) * HH + n], W[(2 * p + 1) * HH + n], hw, lw);
    Wp[n * K + 2 * p]     = hw;
    Wp[n * K + 2 * p + 1] = lw;
}

// ---------- MFMA GEMM: A[N,K] fp32 @ W[K,128] -> out[N,128] bf16 ----------
template<int KT>   // K = KT*32
__global__ __launch_bounds__(256) void k_gemm_mfma(const float* __restrict__ A,
                                                   const uint* __restrict__ Wp,
                                                   ushort* __restrict__ out,
                                                   int N) {
    const int K = KT * 32;
    const int NCH = KT / 2;
    __shared__ uint Bs[128 * 68];
    int tid  = threadIdx.x;
    int wave = tid >> 6;
    int lane = tid & 63;
    int m16  = lane & 15;
    int quad = lane >> 4;
    int row  = blockIdx.x * 64 + wave * 16 + m16;
    int rowc = min(row, N - 1);

    const float4* a4 = (const float4*)(A + (size_t)rowc * K);
    float4 araw[2 * KT];
#pragma unroll
    for (int kt = 0; kt < KT; kt++) {
        araw[2 * kt]     = a4[kt * 8 + quad * 2];
        araw[2 * kt + 1] = a4[kt * 8 + quad * 2 + 1];
    }

    floatx4 acc[8];
#pragma unroll
    for (int c = 0; c < 8; c++) acc[c] = (floatx4){0.f, 0.f, 0.f, 0.f};

    int sn0 = tid >> 4;
    int sq4 = tid & 15;

    for (int ch = 0; ch < NCH; ch++) {
#pragma unroll
        for (int i = 0; i < 8; i++) {
            int n = i * 16 + sn0;
            *(uint4*)&Bs[n * 68 + sq4 * 4] =
                *(const uint4*)&Wp[(size_t)n * K + ch * 64 + sq4 * 4];
        }
        __syncthreads();

#pragma unroll
        for (int ktl = 0; ktl < 2; ktl++) {
            int ktg = ch * 2 + ktl;
            float4 f0 = araw[2 * ktg];
            float4 f1 = araw[2 * ktg + 1];
            uint ahw[4], alw[4];
            splitPair(f0.x, f0.y, ahw[0], alw[0]);
            splitPair(f0.z, f0.w, ahw[1], alw[1]);
            splitPair(f1.x, f1.y, ahw[2], alw[2]);
            splitPair(f1.z, f1.w, ahw[3], alw[3]);
            short8 a_hi = mk8(ahw[0], ahw[1], ahw[2], ahw[3]);
            short8 a_lo = mk8(alw[0], alw[1], alw[2], alw[3]);

#pragma unroll
            for (int c = 0; c < 8; c++) {
                const uint* bp = &Bs[(c * 16 + m16) * 68 + ktl * 32 + quad * 8];
                uint4 w0 = *(const uint4*)bp;
                uint4 w1 = *(const uint4*)(bp + 4);
                short8 b_hi = mk8(w0.x, w0.z, w1.x, w1.z);
                short8 b_lo = mk8(w0.y, w0.w, w1.y, w1.w);
                acc[c] = __builtin_amdgcn_mfma_f32_16x16x32_bf16(a_hi, b_hi, acc[c], 0, 0, 0);
                acc[c] = __builtin_amdgcn_mfma_f32_16x16x32_bf16(a_lo, b_hi, acc[c], 0, 0, 0);
                acc[c] = __builtin_amdgcn_mfma_f32_16x16x32_bf16(a_hi, b_lo, acc[c], 0, 0, 0);
            }
        }
        __syncthreads();
    }

    int rowbase = blockIdx.x * 64 + wave * 16 + quad * 4;
#pragma unroll
    for (int c = 0; c < 8; c++) {
#pragma unroll
        for (int r = 0; r < 4; r++) {
            int rr = rowbase + r;
            if (rr < N) out[(size_t)rr * HH + c * 16 + m16] = f2bf(acc[c][r]);
        }
    }
}

// ---------- CSR aggregation (bf16 gather, quarter-wave rows) ----------
// wave-per-node; lane = q*16+c16: quarter q handles edges j%4==q, lane covers
// 8 cols (one uint4 = 16B). Reduce across quarters via shfl_xor(16/32).
__global__ __launch_bounds__(256) void k_agg(const ushort* __restrict__ xwb,
                                             const float* __restrict__ dinv,
                                             const int* __restrict__ rowptr,
                                             const int* __restrict__ csr_src,
                                             const float* __restrict__ b,
                                             const float* __restrict__ g,
                                             const float* __restrict__ beta,
                                             const float* __restrict__ m,
                                             const float* __restrict__ v,
                                             float* __restrict__ out,
                                             int N, int mode) {
    __shared__ int   sS[256];
    __shared__ float sD[256];
    int wave = threadIdx.x >> 6;
    int lane = threadIdx.x & 63;
    int n = blockIdx.x * 4 + wave;
    if (n >= N) return;
    int wbase = wave * 64;
    int q   = lane >> 4;      // edge phase 0..3
    int c16 = lane & 15;      // 16B col group (8 bf16 cols)

    int beg = rowptr[n];
    int end = rowptr[n + 1];
    float di = dinv[n];
    const uint4* xw4 = (const uint4*)xwb;   // row = 16 x uint4

    float acc[8];
#pragma unroll
    for (int i = 0; i < 8; i++) acc[i] = 0.0f;
    if (q == 0) {
        uint4 w = xw4[(size_t)n * 16 + c16];
        acc[0] = di * bfLo(w.x); acc[1] = di * bfHi(w.x);
        acc[2] = di * bfLo(w.y); acc[3] = di * bfHi(w.y);
        acc[4] = di * bfLo(w.z); acc[5] = di * bfHi(w.z);
        acc[6] = di * bfLo(w.w); acc[7] = di * bfHi(w.w);
    }

    for (int base = beg; base < end; base += 64) {
        int cnt = min(64, end - base);
        if (lane < cnt) {
            int s = csr_src[base + lane];
            sS[wbase + lane] = s;
            sD[wbase + lane] = dinv[s];
        }
        // same-wave LDS write->read (lgkmcnt ordered); no barrier needed
#pragma unroll 4
        for (int j = q; j < cnt; j += 4) {
            int sj   = sS[wbase + j];
            float dj = sD[wbase + j];
            uint4 w = xw4[(size_t)sj * 16 + c16];
            acc[0] = fmaf(dj, bfLo(w.x), acc[0]);
            acc[1] = fmaf(dj, bfHi(w.x), acc[1]);
            acc[2] = fmaf(dj, bfLo(w.y), acc[2]);
            acc[3] = fmaf(dj, bfHi(w.y), acc[3]);
            acc[4] = fmaf(dj, bfLo(w.z), acc[4]);
            acc[5] = fmaf(dj, bfHi(w.z), acc[5]);
            acc[6] = fmaf(dj, bfLo(w.w), acc[6]);
            acc[7] = fmaf(dj, bfHi(w.w), acc[7]);
        }
    }

#pragma unroll
    for (int i = 0; i < 8; i++) {
        acc[i] += __shfl_xor(acc[i], 16, 64);
        acc[i] += __shfl_xor(acc[i], 32, 64);
    }

    if (q == 0) {
        float4 b0 = ((const float4*)b)[c16 * 2];
        float4 b1 = ((const float4*)b)[c16 * 2 + 1];
        float val[8];
        val[0] = di * acc[0] + b0.x; val[1] = di * acc[1] + b0.y;
        val[2] = di * acc[2] + b0.z; val[3] = di * acc[3] + b0.w;
        val[4] = di * acc[4] + b1.x; val[5] = di * acc[5] + b1.y;
        val[6] = di * acc[6] + b1.z; val[7] = di * acc[7] + b1.w;
        if (mode) {
#pragma unroll
            for (int half = 0; half < 2; half++) {
                float4 mm = ((const float4*)m)[c16 * 2 + half];
                float4 vv = ((const float4*)v)[c16 * 2 + half];
                float4 gg = ((const float4*)g)[c16 * 2 + half];
                float4 be = ((const float4*)beta)[c16 * 2 + half];
                int o = half * 4;
                val[o+0] = fmaxf((val[o+0] - mm.x) * rsqrtf(vv.x + BN_EPS) * gg.x + be.x, 0.f);
                val[o+1] = fmaxf((val[o+1] - mm.y) * rsqrtf(vv.y + BN_EPS) * gg.y + be.y, 0.f);
                val[o+2] = fmaxf((val[o+2] - mm.z) * rsqrtf(vv.z + BN_EPS) * gg.z + be.z, 0.f);
                val[o+3] = fmaxf((val[o+3] - mm.w) * rsqrtf(vv.w + BN_EPS) * gg.w + be.w, 0.f);
            }
        }
        float4* o4 = (float4*)(out + (size_t)n * HH + c16 * 8);
        o4[0] = make_float4(val[0], val[1], val[2], val[3]);
        o4[1] = make_float4(val[4], val[5], val[6], val[7]);
    }
}

// ---------- pool ----------
__global__ __launch_bounds__(128) void k_pool(const float* __restrict__ h,
                                              const int* __restrict__ batch,
                                              float* __restrict__ sums,
                                              float* __restrict__ cnts, int N) {
    int col = threadIdx.x;
    int n0 = blockIdx.x * 128;
    int n1 = min(n0 + 128, N);
    float acc = 0.0f;
    float cnt = 0.0f;
    int curg = batch[n0];
    for (int n = n0; n < n1; n++) {
        int gg = batch[n];
        if (gg != curg) {
            atomAddF(&sums[(size_t)curg * HH + col], acc);
            if (col == 0) atomAddF(&cnts[curg], cnt);
            acc = 0.0f; cnt = 0.0f; curg = gg;
        }
        acc += h[(size_t)n * HH + col];
        cnt += 1.0f;
    }
    atomAddF(&sums[(size_t)curg * HH + col], acc);
    if (col == 0) atomAddF(&cnts[curg], cnt);
}

// ---------- classifier head ----------
__global__ __launch_bounds__(64) void k_cls(const float* __restrict__ sums,
                                            const float* __restrict__ cnts,
                                            const float* __restrict__ Wc1,
                                            const float* __restrict__ bc1,
                                            const float* __restrict__ Wc2,
                                            const float* __restrict__ bc2,
                                            float* __restrict__ out, int Hc, int C) {
    int gI = blockIdx.x;
    int tid = threadIdx.x;
    __shared__ float pooled[HH];
    __shared__ float z[64];
    float cnt = fmaxf(cnts[gI], 1.0f);
    for (int c = tid; c < HH; c += 64) pooled[c] = sums[(size_t)gI * HH + c] / cnt;
    __syncthreads();
    if (tid < Hc) {
        float a = bc1[tid];
        for (int k = 0; k < HH; k++) a += pooled[k] * Wc1[k * Hc + tid];
        z[tid] = fmaxf(a, 0.0f);
    }
    __syncthreads();
    if (tid < C) {
        float a = bc2[tid];
        for (int k = 0; k < Hc; k++) a += z[k] * Wc2[k * C + tid];
        out[(size_t)gI * C + tid] = a;
    }
}

extern "C" void kernel_launch(void* const* d_in, const int* in_sizes, int n_in,
                              void* d_out, int out_size, void* d_ws, size_t ws_size,
                              hipStream_t stream) {
    const float* x     = (const float*)d_in[0];
    const int*   ei    = (const int*)d_in[1];
    const int*   batch = (const int*)d_in[2];
    const float* W1    = (const float*)d_in[3];
    const float* b1    = (const float*)d_in[4];
    const float* W2    = (const float*)d_in[5];
    const float* b2    = (const float*)d_in[6];
    const float* W3    = (const float*)d_in[7];
    const float* b3    = (const float*)d_in[8];
    const float* bn1_g = (const float*)d_in[9];
    const float* bn1_b = (const float*)d_in[10];
    const float* bn1_m = (const float*)d_in[11];
    const float* bn1_v = (const float*)d_in[12];
    const float* bn2_g = (const float*)d_in[13];
    const float* bn2_b = (const float*)d_in[14];
    const float* bn2_m = (const float*)d_in[15];
    const float* bn2_v = (const float*)d_in[16];
    const float* Wc1   = (const float*)d_in[17];
    const float* bc1   = (const float*)d_in[18];
    const float* Wc2   = (const float*)d_in[19];
    const float* bc2   = (const float*)d_in[20];
    float* out = (float*)d_out;

    const int N  = in_sizes[2];
    const int E  = in_sizes[1] / 2;
    const int K0 = in_sizes[0] / N;      // 256
    const int Hc = in_sizes[18];         // 64
    const int C  = in_sizes[20];         // 16
    const int G  = out_size / C;         // 64

    const int* srcv = ei;
    const int* dstv = ei + E;

    // workspace layout (int/float units; offsets 256-multiples)
    float* ws = (float*)d_ws;
    size_t NH = (size_t)N * HH;
    size_t Na = (((size_t)N + 255) / 256) * 256;
    size_t Ea = (((size_t)E + 255) / 256) * 256;
    ushort* bufA   = (ushort*)ws;            // N*128 bf16 (half the NH slot)
    float* bufB    = ws + NH;
    float* dinv    = bufB + NH;
    int*   degInt  = (int*)(dinv + Na);
    int*   rowptr  = degInt + Na;            // N+1
    int*   csr_src = rowptr + Na + 256;
    uint2* bucketed= (uint2*)(csr_src + Ea); // E * 8B
    int*   gH      = (int*)(bucketed + Ea);  // 65536
    int*   gC      = gH + 65536;             // 65536
    int*   totals  = gC + 65536;             // 256
    int*   baseArr = totals + 256;           // 257 (pad 512)
    int*   partials= baseArr + 512;          // 256
    float* sums    = (float*)(partials + 256);
    float* cnts    = sums + (size_t)G * HH;  // pad 256
    uint*  Wp1     = (uint*)(cnts + 256);
    uint*  Wp2     = Wp1 + (size_t)K0 * HH;
    uint*  Wp3     = Wp2 + (size_t)HH * HH;

    int tile = (E + 255) / 256;
    int nb   = (int)((N + 255) / 256);
    int gGemm = (N + 63) / 64;
    int gAgg  = (N + 3) / 4;
    int gPool = (N + 127) / 128;

    // ---- CSR build (no global atomics) ----
    k_ahist<<<256, 256, 0, stream>>>(dstv, gH, E, tile);
    k_scan1<<<256, 256, 0, stream>>>(gH, gC, totals);
    k_scan2<<<1, 256, 0, stream>>>(totals, baseArr);
    k_asc<<<256, 256, 0, stream>>>(srcv, dstv, gC, baseArr, bucketed, E, tile);
    k_bdeg<<<256, 256, 0, stream>>>(bucketed, baseArr, degInt, dinv, N);
    k_scanA<<<nb, 256, 0, stream>>>(degInt, partials, N);
    k_scanB<<<1, 256, 0, stream>>>(partials, nb);
    k_scanC<<<nb, 256, 0, stream>>>(degInt, partials, rowptr, N);
    k_csc<<<256, 256, 0, stream>>>(bucketed, baseArr, rowptr, csr_src, N);

    // ---- weight splits ----
    k_wsplit<<<(128 * (K0 / 2) + 255) / 256, 256, 0, stream>>>(W1, Wp1, K0);
    k_wsplit<<<(128 * (HH / 2) + 255) / 256, 256, 0, stream>>>(W2, Wp2, HH);
    k_wsplit<<<(128 * (HH / 2) + 255) / 256, 256, 0, stream>>>(W3, Wp3, HH);

    // ---- layer 1 ----
    if (K0 == 256)
        k_gemm_mfma<8><<<gGemm, 256, 0, stream>>>(x, Wp1, bufA, N);
    else
        k_gemm_mfma<4><<<gGemm, 256, 0, stream>>>(x, Wp1, bufA, N);
    k_agg<<<gAgg, 256, 0, stream>>>(bufA, dinv, rowptr, csr_src, b1,
                                    bn1_g, bn1_b, bn1_m, bn1_v, bufB, N, 1);
    // ---- layer 2 ----
    k_gemm_mfma<4><<<gGemm, 256, 0, stream>>>(bufB, Wp2, bufA, N);
    k_agg<<<gAgg, 256, 0, stream>>>(bufA, dinv, rowptr, csr_src, b2,
                                    bn2_g, bn2_b, bn2_m, bn2_v, bufB, N, 1);
    // ---- layer 3 ----
    k_gemm_mfma<4><<<gGemm, 256, 0, stream>>>(bufB, Wp3, bufA, N);
    k_agg<<<gAgg, 256, 0, stream>>>(bufA, dinv, rowptr, csr_src, b3,
                                    nullptr, nullptr, nullptr, nullptr, bufB, N, 0);

    // ---- pool + classifier ----
    hipMemsetAsync(sums, 0, ((size_t)G * HH + G) * sizeof(float), stream);
    k_pool<<<gPool, 128, 0, stream>>>(bufB, batch, sums, cnts, N);
    k_cls<<<G, 64, 0, stream>>>(sums, cnts, Wc1, bc1, Wc2, bc2, out, Hc, C);
}